// Round 11
// baseline (979.212 us; speedup 1.0000x reference)
//
#include <hip/hip_runtime.h>
#include <hip/hip_bf16.h>
#include <hip/hip_cooperative_groups.h>

namespace cg = cooperative_groups;

#define NN 50000
#define NE 800000
#define BN_EPS 1e-5f
#define CHUNK 4096
#define NCH 196     // ceil(NE/CHUNK)
#define GRID 512    // 2 blocks/CU x 256 CUs -- safely co-resident
#define PREPV (NCH + 3125 + 5)  // 3326 virtual blocks in prep stage
#define MGRID 782   // ceil(NN/64)

typedef __attribute__((ext_vector_type(4))) float f32x4;
typedef __attribute__((ext_vector_type(8))) short s16x8;
typedef __attribute__((ext_vector_type(4))) short s16x4;

__device__ __forceinline__ float bf2f(__hip_bfloat16 v) { return __bfloat162float(v); }
__device__ __forceinline__ short f2bs(float v) {
    __hip_bfloat16 b = __float2bfloat16(v);
    return __builtin_bit_cast(short, b);
}

struct P {
    const int* src; const int* dst;
    int* part; float* sums;
    int* bbase; int* bres; int* off; int* adj; int* ebuf;
    const float* x;
    __hip_bfloat16* Xb; __hip_bfloat16* AGGb; __hip_bfloat16* HCb;
    float* T; float* T2;
    const float *w0a, *w0b, *w1a, *w1b, *lw;
    short *Wt0a, *Wt0b, *Wt1a, *Wt1b, *Wtf;
    const float *b0a, *g0a, *be0a, *b0b, *g0b, *be0b;
    const float *b1a, *g1a, *be1a, *b1b, *g1b, *be1b;
    const float* lb;
    float* out;
};

union SMem {
    int hist_c[256];
    int scan_s[256];
    struct { int cnt[256], loff[256], lcur[256], gst[256], sc[256]; int packed[CHUNK]; } sca;
    struct { float sc[64], sh[64], lsum[64], lssq[64]; } bn;
};

// ---------------- stage device functions (shared by fused + fallback) ----------

__device__ __forceinline__ void stage_prep(int vb, int t, SMem& u, const P& p) {
    if (vb < NCH) {
        __syncthreads();
        u.hist_c[t] = 0;
        __syncthreads();
        int base = vb * CHUNK;
        int n = NE - base; if (n > CHUNK) n = CHUNK;
        for (int i = t; i < n; i += 256) atomicAdd(&u.hist_c[p.dst[base + i] >> 8], 1);
        __syncthreads();
        p.part[vb * 256 + t] = u.hist_c[t];
        __syncthreads();
    } else if (vb < NCH + 3125) {
        int i = (vb - NCH) * 256 + t;
        if (i < NN * 16) {
            f32x4 v = *(const f32x4*)(p.x + (size_t)i * 4);
            s16x4 ov;
            #pragma unroll
            for (int j = 0; j < 4; j++) ov[j] = f2bs(v[j]);
            *(s16x4*)((short*)p.Xb + (size_t)i * 4) = ov;
        }
    } else {
        int wb = vb - (NCH + 3125);
        if (wb < 4) {
            const float* W = wb == 0 ? p.w0a : wb == 1 ? p.w0b : wb == 2 ? p.w1a : p.w1b;
            short* Wt = wb == 0 ? p.Wt0a : wb == 1 ? p.Wt0b : wb == 2 ? p.Wt1a : p.Wt1b;
            for (int e = t; e < 4096; e += 256) {
                int k = e >> 6, n = e & 63;
                Wt[n * 64 + k] = f2bs(W[e]);
            }
        } else {
            for (int e = t; e < 8192; e += 256) {
                int k = e >> 6, n = e & 63;
                p.Wtf[n * 128 + k] = f2bs(p.lw[e]);
            }
        }
    }
}

__device__ __forceinline__ void stage_scan(int t, SMem& u, const P& p) {
    int v = 0;
    for (int c = 0; c < NCH; c++) v += p.part[c * 256 + t];
    u.scan_s[t] = v;
    __syncthreads();
    for (int d = 1; d < 256; d <<= 1) {
        int uu = (t >= d) ? u.scan_s[t - d] : 0;
        __syncthreads();
        u.scan_s[t] += uu;
        __syncthreads();
    }
    int ex = u.scan_s[t] - v;
    p.bbase[t] = ex;
    p.bres[t] = ex;
    if (t == 0) { p.bbase[256] = NE; p.off[NN] = NE; }
    p.sums[t] = 0.f;
    p.sums[256 + t] = 0.f;
}

__device__ __forceinline__ void stage_scatter(int vb, int t, SMem& u, const P& p) {
    __syncthreads();
    u.sca.cnt[t] = 0;
    __syncthreads();
    int base = vb * CHUNK;
    int n = NE - base; if (n > CHUNK) n = CHUNK;
    for (int i = t; i < n; i += 256) atomicAdd(&u.sca.cnt[p.dst[base + i] >> 8], 1);
    __syncthreads();
    u.sca.sc[t] = u.sca.cnt[t];
    __syncthreads();
    for (int d = 1; d < 256; d <<= 1) {
        int uu = (t >= d) ? u.sca.sc[t - d] : 0;
        __syncthreads();
        u.sca.sc[t] += uu;
        __syncthreads();
    }
    u.sca.loff[t] = u.sca.sc[t] - u.sca.cnt[t];
    u.sca.lcur[t] = u.sca.loff[t];
    __syncthreads();
    for (int i = t; i < n; i += 256) {
        int d = p.dst[base + i];
        int bk = d >> 8;
        int pos = atomicAdd(&u.sca.lcur[bk], 1);
        u.sca.packed[pos] = p.src[base + i] | ((d & 255) << 16) | (bk << 24);
    }
    __syncthreads();
    if (u.sca.cnt[t]) u.sca.gst[t] = atomicAdd(&p.bres[t], u.sca.cnt[t]);
    __syncthreads();
    for (int i = t; i < n; i += 256) {
        int v = u.sca.packed[i];
        int bk = (v >> 24) & 255;
        p.ebuf[u.sca.gst[bk] + i - u.sca.loff[bk]] = v & 0xFFFFFF;
    }
    __syncthreads();
}

__device__ __forceinline__ void stage_csr(int vb, int t, SMem& u, const P& p) {
    __syncthreads();
    int s0 = p.bbase[vb], s1 = p.bbase[vb + 1];
    int n = s1 - s0;
    u.sca.cnt[t] = 0;
    __syncthreads();
    for (int i = t; i < n; i += 256) atomicAdd(&u.sca.cnt[(p.ebuf[s0 + i] >> 16) & 255], 1);
    __syncthreads();
    u.sca.sc[t] = u.sca.cnt[t];
    __syncthreads();
    for (int d = 1; d < 256; d <<= 1) {
        int uu = (t >= d) ? u.sca.sc[t - d] : 0;
        __syncthreads();
        u.sca.sc[t] += uu;
        __syncthreads();
    }
    u.sca.loff[t] = u.sca.sc[t] - u.sca.cnt[t];
    u.sca.lcur[t] = u.sca.loff[t];
    int node = vb * 256 + t;
    if (node < NN) p.off[node] = s0 + u.sca.loff[t];
    __syncthreads();
    for (int i = t; i < n; i += 256) {
        int v = p.ebuf[s0 + i];
        int pos = atomicAdd(&u.sca.lcur[(v >> 16) & 255], 1);
        p.adj[s0 + pos] = v & 0xFFFF;
    }
    __syncthreads();
}

__device__ __forceinline__ float gather_row(const __hip_bfloat16* __restrict__ X,
                                            int lane, const int* __restrict__ off,
                                            const int* __restrict__ adj, int node) {
    float acc = bf2f(X[(size_t)node * 64 + lane]);
    int s = off[node], e = off[node + 1];
    int p = s;
    for (; p + 8 <= e; p += 8) {
        int j0 = adj[p + 0], j1 = adj[p + 1], j2 = adj[p + 2], j3 = adj[p + 3];
        int j4 = adj[p + 4], j5 = adj[p + 5], j6 = adj[p + 6], j7 = adj[p + 7];
        float v0 = bf2f(X[(size_t)j0 * 64 + lane]);
        float v1 = bf2f(X[(size_t)j1 * 64 + lane]);
        float v2 = bf2f(X[(size_t)j2 * 64 + lane]);
        float v3 = bf2f(X[(size_t)j3 * 64 + lane]);
        float v4 = bf2f(X[(size_t)j4 * 64 + lane]);
        float v5 = bf2f(X[(size_t)j5 * 64 + lane]);
        float v6 = bf2f(X[(size_t)j6 * 64 + lane]);
        float v7 = bf2f(X[(size_t)j7 * 64 + lane]);
        acc += ((v0 + v1) + (v2 + v3)) + ((v4 + v5) + (v6 + v7));
    }
    if (p + 4 <= e) {
        int j0 = adj[p + 0], j1 = adj[p + 1], j2 = adj[p + 2], j3 = adj[p + 3];
        float v0 = bf2f(X[(size_t)j0 * 64 + lane]);
        float v1 = bf2f(X[(size_t)j1 * 64 + lane]);
        float v2 = bf2f(X[(size_t)j2 * 64 + lane]);
        float v3 = bf2f(X[(size_t)j3 * 64 + lane]);
        acc += (v0 + v1) + (v2 + v3);
        p += 4;
    }
    for (; p < e; p++) acc += bf2f(X[(size_t)adj[p] * 64 + lane]);
    return acc;
}

__device__ __forceinline__ void bn_coeff(int t, const float* __restrict__ stats,
                                         const float* __restrict__ g,
                                         const float* __restrict__ be,
                                         float* sc, float* sh) {
    if (t < 64) {
        float m = stats[t] * (1.0f / NN);
        float var = stats[64 + t] * (1.0f / NN) - m * m;
        if (var < 0.f) var = 0.f;
        float s = g[t] * rsqrtf(var + BN_EPS);
        sc[t] = s;
        sh[t] = be[t] - m * s;
    }
}

__device__ __forceinline__ void stage_gemm_a(int B, int t, const __hip_bfloat16* Ab,
                                             const short* Wt, const float* bias,
                                             float* T, float* sums, SMem& u) {
    __syncthreads();
    if (t < 64) { u.bn.lsum[t] = 0.f; u.bn.lssq[t] = 0.f; }
    __syncthreads();
    int wv = t >> 6, L = t & 63;
    int m = L & 15, quad = L >> 4;
    int wrow = B * 64 + wv * 16;
    int arow = wrow + m;
    if (arow >= NN) arow = NN - 1;
    const short* Ap = (const short*)Ab;
    s16x8 a0 = *(const s16x8*)(Ap + (size_t)arow * 64 + quad * 8);
    s16x8 a1 = *(const s16x8*)(Ap + (size_t)arow * 64 + 32 + quad * 8);
    f32x4 acc[4];
    #pragma unroll
    for (int nt = 0; nt < 4; nt++) {
        int n = nt * 16 + m;
        s16x8 b0 = *(const s16x8*)(Wt + n * 64 + quad * 8);
        s16x8 b1 = *(const s16x8*)(Wt + n * 64 + 32 + quad * 8);
        acc[nt] = (f32x4){0.f, 0.f, 0.f, 0.f};
        acc[nt] = __builtin_amdgcn_mfma_f32_16x16x32_bf16(a0, b0, acc[nt], 0, 0, 0);
        acc[nt] = __builtin_amdgcn_mfma_f32_16x16x32_bf16(a1, b1, acc[nt], 0, 0, 0);
    }
    #pragma unroll
    for (int nt = 0; nt < 4; nt++) {
        int col = nt * 16 + m;
        float bv = bias[col];
        float ps = 0.f, pq = 0.f;
        #pragma unroll
        for (int r = 0; r < 4; r++) {
            int orow = wrow + quad * 4 + r;
            if (orow < NN) {
                float v = acc[nt][r] + bv;
                T[(size_t)orow * 64 + col] = v;
                ps += v;
                pq += v * v;
            }
        }
        atomicAdd(&u.bn.lsum[col], ps);
        atomicAdd(&u.bn.lssq[col], pq);
    }
    __syncthreads();
    if (t < 64) {
        atomicAdd(&sums[t], u.bn.lsum[t]);
        atomicAdd(&sums[64 + t], u.bn.lssq[t]);
    }
}

__device__ __forceinline__ void stage_gemm_bn(int B, int t, const float* Tin,
                                              const float* stats, const float* g,
                                              const float* be, const short* Wt,
                                              const float* bias, float* T, float* sums,
                                              SMem& u) {
    __syncthreads();
    bn_coeff(t, stats, g, be, u.bn.sc, u.bn.sh);
    if (t < 64) { u.bn.lsum[t] = 0.f; u.bn.lssq[t] = 0.f; }
    __syncthreads();
    int wv = t >> 6, L = t & 63;
    int m = L & 15, quad = L >> 4;
    int wrow = B * 64 + wv * 16;
    int arow = wrow + m;
    if (arow >= NN) arow = NN - 1;
    f32x4 t0 = *(const f32x4*)(Tin + (size_t)arow * 64 + quad * 8);
    f32x4 t1 = *(const f32x4*)(Tin + (size_t)arow * 64 + quad * 8 + 4);
    f32x4 t2 = *(const f32x4*)(Tin + (size_t)arow * 64 + 32 + quad * 8);
    f32x4 t3 = *(const f32x4*)(Tin + (size_t)arow * 64 + 32 + quad * 8 + 4);
    s16x8 a0, a1;
    #pragma unroll
    for (int j = 0; j < 4; j++) {
        int k0 = quad * 8 + j, k1 = quad * 8 + 4 + j;
        float u0 = t0[j] * u.bn.sc[k0] + u.bn.sh[k0]; a0[j]     = f2bs(u0 > 0.f ? u0 : 0.f);
        float u1 = t1[j] * u.bn.sc[k1] + u.bn.sh[k1]; a0[4 + j] = f2bs(u1 > 0.f ? u1 : 0.f);
        float u2 = t2[j] * u.bn.sc[32 + k0] + u.bn.sh[32 + k0]; a1[j]     = f2bs(u2 > 0.f ? u2 : 0.f);
        float u3 = t3[j] * u.bn.sc[32 + k1] + u.bn.sh[32 + k1]; a1[4 + j] = f2bs(u3 > 0.f ? u3 : 0.f);
    }
    f32x4 acc[4];
    #pragma unroll
    for (int nt = 0; nt < 4; nt++) {
        int n = nt * 16 + m;
        s16x8 b0 = *(const s16x8*)(Wt + n * 64 + quad * 8);
        s16x8 b1 = *(const s16x8*)(Wt + n * 64 + 32 + quad * 8);
        acc[nt] = (f32x4){0.f, 0.f, 0.f, 0.f};
        acc[nt] = __builtin_amdgcn_mfma_f32_16x16x32_bf16(a0, b0, acc[nt], 0, 0, 0);
        acc[nt] = __builtin_amdgcn_mfma_f32_16x16x32_bf16(a1, b1, acc[nt], 0, 0, 0);
    }
    #pragma unroll
    for (int nt = 0; nt < 4; nt++) {
        int col = nt * 16 + m;
        float bv = bias[col];
        float ps = 0.f, pq = 0.f;
        #pragma unroll
        for (int r = 0; r < 4; r++) {
            int orow = wrow + quad * 4 + r;
            if (orow < NN) {
                float v = acc[nt][r] + bv;
                T[(size_t)orow * 64 + col] = v;
                ps += v;
                pq += v * v;
            }
        }
        atomicAdd(&u.bn.lsum[col], ps);
        atomicAdd(&u.bn.lssq[col], pq);
    }
    __syncthreads();
    if (t < 64) {
        atomicAdd(&sums[t], u.bn.lsum[t]);
        atomicAdd(&sums[64 + t], u.bn.lssq[t]);
    }
}

__device__ __forceinline__ void stage_fin(int B, int t, SMem& u, const P& p) {
    // u.bn.sc/sh must already hold the h2 BN coefficients
    int wv = t >> 6, L = t & 63;
    int m = L & 15, quad = L >> 4;
    int wrow = B * 64 + wv * 16;
    int arow = wrow + m;
    if (arow >= NN) arow = NN - 1;
    const short* Hp = (const short*)p.HCb;
    s16x8 a0 = *(const s16x8*)(Hp + (size_t)arow * 64 + quad * 8);
    s16x8 a1 = *(const s16x8*)(Hp + (size_t)arow * 64 + 32 + quad * 8);
    f32x4 t0 = *(const f32x4*)(p.T2 + (size_t)arow * 64 + quad * 8);
    f32x4 t1 = *(const f32x4*)(p.T2 + (size_t)arow * 64 + quad * 8 + 4);
    f32x4 t2 = *(const f32x4*)(p.T2 + (size_t)arow * 64 + 32 + quad * 8);
    f32x4 t3 = *(const f32x4*)(p.T2 + (size_t)arow * 64 + 32 + quad * 8 + 4);
    s16x8 a2, a3;
    #pragma unroll
    for (int j = 0; j < 4; j++) {
        int k0 = quad * 8 + j, k1 = quad * 8 + 4 + j;
        float u0 = t0[j] * u.bn.sc[k0] + u.bn.sh[k0]; a2[j]     = f2bs(u0 > 0.f ? u0 : 0.f);
        float u1 = t1[j] * u.bn.sc[k1] + u.bn.sh[k1]; a2[4 + j] = f2bs(u1 > 0.f ? u1 : 0.f);
        float u2 = t2[j] * u.bn.sc[32 + k0] + u.bn.sh[32 + k0]; a3[j]     = f2bs(u2 > 0.f ? u2 : 0.f);
        float u3 = t3[j] * u.bn.sc[32 + k1] + u.bn.sh[32 + k1]; a3[4 + j] = f2bs(u3 > 0.f ? u3 : 0.f);
    }
    f32x4 acc[4];
    #pragma unroll
    for (int nt = 0; nt < 4; nt++) {
        int n = nt * 16 + m;
        s16x8 b0 = *(const s16x8*)(p.Wtf + n * 128 + quad * 8);
        s16x8 b1 = *(const s16x8*)(p.Wtf + n * 128 + 32 + quad * 8);
        s16x8 b2 = *(const s16x8*)(p.Wtf + n * 128 + 64 + quad * 8);
        s16x8 b3 = *(const s16x8*)(p.Wtf + n * 128 + 96 + quad * 8);
        acc[nt] = (f32x4){0.f, 0.f, 0.f, 0.f};
        acc[nt] = __builtin_amdgcn_mfma_f32_16x16x32_bf16(a0, b0, acc[nt], 0, 0, 0);
        acc[nt] = __builtin_amdgcn_mfma_f32_16x16x32_bf16(a1, b1, acc[nt], 0, 0, 0);
        acc[nt] = __builtin_amdgcn_mfma_f32_16x16x32_bf16(a2, b2, acc[nt], 0, 0, 0);
        acc[nt] = __builtin_amdgcn_mfma_f32_16x16x32_bf16(a3, b3, acc[nt], 0, 0, 0);
    }
    #pragma unroll
    for (int nt = 0; nt < 4; nt++) {
        int col = nt * 16 + m;
        float bv = p.lb[col];
        #pragma unroll
        for (int r = 0; r < 4; r++) {
            int orow = wrow + quad * 4 + r;
            if (orow < NN) p.out[(size_t)orow * 64 + col] = acc[nt][r] + bv;
        }
    }
}

// ================= fused cooperative kernel =================
__global__ void __launch_bounds__(256) fused_k(P p) {
    cg::grid_group grid = cg::this_grid();
    __shared__ SMem u;
    int B = blockIdx.x, t = threadIdx.x, G = gridDim.x;
    int lane = t & 63, wv = t >> 6;

    for (int vb = B; vb < PREPV; vb += G) stage_prep(vb, t, u, p);
    grid.sync();
    if (B == 0) stage_scan(t, u, p);
    grid.sync();
    for (int vb = B; vb < NCH; vb += G) stage_scatter(vb, t, u, p);
    grid.sync();
    for (int vb = B; vb < NCH; vb += G) stage_csr(vb, t, u, p);
    grid.sync();
    for (int vb = B; vb < 12500; vb += G) {
        int node = vb * 4 + wv;
        if (node < NN) {
            float acc = gather_row(p.Xb, lane, p.off, p.adj, node);
            p.AGGb[(size_t)node * 64 + lane] = __float2bfloat16(acc);
        }
    }
    grid.sync();
    for (int vb = B; vb < MGRID; vb += G)
        stage_gemm_a(vb, t, p.AGGb, p.Wt0a, p.b0a, p.T, p.sums + 0, u);
    grid.sync();
    for (int vb = B; vb < MGRID; vb += G)
        stage_gemm_bn(vb, t, p.T, p.sums + 0, p.g0a, p.be0a, p.Wt0b, p.b0b,
                      p.T2, p.sums + 128, u);
    grid.sync();
    __syncthreads();
    bn_coeff(t, p.sums + 128, p.g0b, p.be0b, u.bn.sc, u.bn.sh);
    __syncthreads();
    for (int vb = B; vb < 3125; vb += G) {
        int i = vb * 256 + t;
        if (i < NN * 16) {
            int row = i >> 4, f = (i & 15) * 4;
            f32x4 v = *(const f32x4*)(p.T2 + (size_t)row * 64 + f);
            s16x4 ub;
            #pragma unroll
            for (int j = 0; j < 4; j++) {
                float w = v[j] * u.bn.sc[f + j] + u.bn.sh[f + j];
                ub[j] = f2bs(w > 0.f ? w : 0.f);
            }
            *(s16x4*)((short*)p.HCb + (size_t)row * 64 + f) = ub;
        }
    }
    grid.sync();
    for (int vb = B; vb < 12500; vb += G) {
        int node = vb * 4 + wv;
        if (node < NN) {
            float acc = gather_row(p.HCb, lane, p.off, p.adj, node);
            p.AGGb[(size_t)node * 64 + lane] = __float2bfloat16(acc);
        }
    }
    grid.sync();
    for (int vb = B; vb < MGRID; vb += G)
        stage_gemm_a(vb, t, p.AGGb, p.Wt1a, p.b1a, p.T, p.sums + 256, u);
    grid.sync();
    for (int vb = B; vb < MGRID; vb += G)
        stage_gemm_bn(vb, t, p.T, p.sums + 256, p.g1a, p.be1a, p.Wt1b, p.b1b,
                      p.T2, p.sums + 384, u);
    grid.sync();
    __syncthreads();
    bn_coeff(t, p.sums + 384, p.g1b, p.be1b, u.bn.sc, u.bn.sh);
    __syncthreads();
    for (int vb = B; vb < MGRID; vb += G) stage_fin(vb, t, u, p);
}

// ================= fallback wrappers (used only if coop launch fails) ==========
__global__ void prep_w(P p)  { __shared__ SMem u; stage_prep(blockIdx.x, threadIdx.x, u, p); }
__global__ void scan_w(P p)  { __shared__ SMem u; stage_scan(threadIdx.x, u, p); }
__global__ void scat_w(P p)  { __shared__ SMem u; stage_scatter(blockIdx.x, threadIdx.x, u, p); }
__global__ void csrb_w(P p)  { __shared__ SMem u; stage_csr(blockIdx.x, threadIdx.x, u, p); }
__global__ void gath_w(P p, int layer) {
    int node = blockIdx.x * 4 + (threadIdx.x >> 6);
    int lane = threadIdx.x & 63;
    if (node >= NN) return;
    const __hip_bfloat16* X = layer == 0 ? p.Xb : p.HCb;
    float acc = gather_row(X, lane, p.off, p.adj, node);
    p.AGGb[(size_t)node * 64 + lane] = __float2bfloat16(acc);
}
__global__ void gemma_w(P p, int layer) {
    __shared__ SMem u;
    if (layer == 0) stage_gemm_a(blockIdx.x, threadIdx.x, p.AGGb, p.Wt0a, p.b0a, p.T, p.sums + 0, u);
    else            stage_gemm_a(blockIdx.x, threadIdx.x, p.AGGb, p.Wt1a, p.b1a, p.T, p.sums + 256, u);
}
__global__ void gemmbn_w(P p, int layer) {
    __shared__ SMem u;
    if (layer == 0) stage_gemm_bn(blockIdx.x, threadIdx.x, p.T, p.sums + 0, p.g0a, p.be0a,
                                  p.Wt0b, p.b0b, p.T2, p.sums + 128, u);
    else            stage_gemm_bn(blockIdx.x, threadIdx.x, p.T, p.sums + 256, p.g1a, p.be1a,
                                  p.Wt1b, p.b1b, p.T2, p.sums + 384, u);
}
__global__ void bnfin_w(P p) {
    __shared__ SMem u;
    int t = threadIdx.x;
    bn_coeff(t, p.sums + 128, p.g0b, p.be0b, u.bn.sc, u.bn.sh);
    __syncthreads();
    int i = blockIdx.x * 256 + t;
    if (i < NN * 16) {
        int row = i >> 4, f = (i & 15) * 4;
        f32x4 v = *(const f32x4*)(p.T2 + (size_t)row * 64 + f);
        s16x4 ub;
        #pragma unroll
        for (int j = 0; j < 4; j++) {
            float w = v[j] * u.bn.sc[f + j] + u.bn.sh[f + j];
            ub[j] = f2bs(w > 0.f ? w : 0.f);
        }
        *(s16x4*)((short*)p.HCb + (size_t)row * 64 + f) = ub;
    }
}
__global__ void fin_w(P p) {
    __shared__ SMem u;
    int t = threadIdx.x;
    bn_coeff(t, p.sums + 384, p.g1b, p.be1b, u.bn.sc, u.bn.sh);
    __syncthreads();
    stage_fin(blockIdx.x, t, u, p);
}

// ---------------- launch ----------------
extern "C" void kernel_launch(void* const* d_in, const int* in_sizes, int n_in,
                              void* d_out, int out_size, void* d_ws, size_t ws_size,
                              hipStream_t stream) {
    (void)in_sizes; (void)n_in; (void)out_size; (void)ws_size;
    const int* ei = (const int*)d_in[1];

    char* wsb = (char*)d_ws;
    size_t o = 0;
    auto alloc = [&](size_t bytes) -> char* {
        char* ptr = wsb + o;
        o += (bytes + 255) & ~(size_t)255;
        return ptr;
    };

    P p;
    p.src = ei;
    p.dst = ei + NE;
    p.part  = (int*)alloc(NCH * 256 * 4);
    p.sums  = (float*)alloc(512 * 4);
    p.bbase = (int*)alloc(257 * 4);
    p.bres  = (int*)alloc(256 * 4);
    p.off   = (int*)alloc((NN + 1) * 4);
    p.adj   = (int*)alloc(NE * 4);
    p.ebuf  = (int*)alloc(NE * 4);
    p.Xb    = (__hip_bfloat16*)alloc((size_t)NN * 64 * 2);
    p.AGGb  = (__hip_bfloat16*)alloc((size_t)NN * 64 * 2);
    p.HCb   = (__hip_bfloat16*)alloc((size_t)NN * 64 * 2);
    p.T     = (float*)alloc((size_t)NN * 64 * 4);
    p.T2    = (float*)alloc((size_t)NN * 64 * 4);
    p.Wt0a  = (short*)alloc(4096 * 2);
    p.Wt0b  = (short*)alloc(4096 * 2);
    p.Wt1a  = (short*)alloc(4096 * 2);
    p.Wt1b  = (short*)alloc(4096 * 2);
    p.Wtf   = (short*)alloc(8192 * 2);

    p.x   = (const float*)d_in[0];
    p.w0a = (const float*)d_in[2];  p.b0a = (const float*)d_in[3];
    p.g0a = (const float*)d_in[4];  p.be0a = (const float*)d_in[5];
    p.w0b = (const float*)d_in[6];  p.b0b = (const float*)d_in[7];
    p.g0b = (const float*)d_in[8];  p.be0b = (const float*)d_in[9];
    p.w1a = (const float*)d_in[10]; p.b1a = (const float*)d_in[11];
    p.g1a = (const float*)d_in[12]; p.be1a = (const float*)d_in[13];
    p.w1b = (const float*)d_in[14]; p.b1b = (const float*)d_in[15];
    p.g1b = (const float*)d_in[16]; p.be1b = (const float*)d_in[17];
    p.lw  = (const float*)d_in[18]; p.lb = (const float*)d_in[19];
    p.out = (float*)d_out;

    void* args[] = { &p };
    hipError_t err = hipLaunchCooperativeKernel(reinterpret_cast<void*>(fused_k),
                                                dim3(GRID), dim3(256), args, 0, stream);
    if (err != hipSuccess) {
        (void)hipGetLastError();  // clear sticky error; fall back to multi-kernel path
        prep_w  <<<PREPV, 256, 0, stream>>>(p);
        scan_w  <<<1,     256, 0, stream>>>(p);
        scat_w  <<<NCH,   256, 0, stream>>>(p);
        csrb_w  <<<NCH,   256, 0, stream>>>(p);
        gath_w  <<<12500, 256, 0, stream>>>(p, 0);
        gemma_w <<<MGRID, 256, 0, stream>>>(p, 0);
        gemmbn_w<<<MGRID, 256, 0, stream>>>(p, 0);
        bnfin_w <<<3125,  256, 0, stream>>>(p);
        gath_w  <<<12500, 256, 0, stream>>>(p, 1);
        gemma_w <<<MGRID, 256, 0, stream>>>(p, 1);
        gemmbn_w<<<MGRID, 256, 0, stream>>>(p, 1);
        fin_w   <<<MGRID, 256, 0, stream>>>(p);
    }
}

// Round 12
// 973.309 us; speedup vs baseline: 1.0061x; 1.0061x over previous
//
#include <hip/hip_runtime.h>
#include <hip/hip_bf16.h>
#include <hip/hip_cooperative_groups.h>

namespace cg = cooperative_groups;

#define NN 50000
#define NE 800000
#define BN_EPS 1e-5f
#define CHUNK 4096
#define NCH 196     // ceil(NE/CHUNK)
#define GRID_MIN 512
#define GRID_MAX 1792   // 7 blocks/CU x 256 CUs (LDS 21.25KB, VGPR 68 both allow 7)
#define PREPV (NCH + 3125 + 5)  // 3326 virtual blocks in prep stage
#define MGRID 782   // ceil(NN/64)

typedef __attribute__((ext_vector_type(4))) float f32x4;
typedef __attribute__((ext_vector_type(8))) short s16x8;
typedef __attribute__((ext_vector_type(4))) short s16x4;

__device__ __forceinline__ float bf2f(__hip_bfloat16 v) { return __bfloat162float(v); }
__device__ __forceinline__ short f2bs(float v) {
    __hip_bfloat16 b = __float2bfloat16(v);
    return __builtin_bit_cast(short, b);
}

struct P {
    const int* src; const int* dst;
    int* part; float* sums;
    int* bbase; int* bres; int* off; int* adj; int* ebuf;
    const float* x;
    __hip_bfloat16* Xb; __hip_bfloat16* AGGb; __hip_bfloat16* HCb;
    float* T; float* T2;
    const float *w0a, *w0b, *w1a, *w1b, *lw;
    short *Wt0a, *Wt0b, *Wt1a, *Wt1b, *Wtf;
    const float *b0a, *g0a, *be0a, *b0b, *g0b, *be0b;
    const float *b1a, *g1a, *be1a, *b1b, *g1b, *be1b;
    const float* lb;
    float* out;
};

union SMem {
    int hist_c[256];
    int scan_s[256];
    struct { int cnt[256], loff[256], lcur[256], gst[256], sc[256]; int packed[CHUNK]; } sca;
    struct { float sc[64], sh[64], lsum[64], lssq[64]; } bn;
};

// ---------------- stage device functions (shared by fused + fallback) ----------

__device__ __forceinline__ void stage_prep(int vb, int t, SMem& u, const P& p) {
    if (vb < NCH) {
        __syncthreads();
        u.hist_c[t] = 0;
        __syncthreads();
        int base = vb * CHUNK;
        int n = NE - base; if (n > CHUNK) n = CHUNK;
        for (int i = t; i < n; i += 256) atomicAdd(&u.hist_c[p.dst[base + i] >> 8], 1);
        __syncthreads();
        p.part[vb * 256 + t] = u.hist_c[t];
        __syncthreads();
    } else if (vb < NCH + 3125) {
        int i = (vb - NCH) * 256 + t;
        if (i < NN * 16) {
            f32x4 v = *(const f32x4*)(p.x + (size_t)i * 4);
            s16x4 ov;
            #pragma unroll
            for (int j = 0; j < 4; j++) ov[j] = f2bs(v[j]);
            *(s16x4*)((short*)p.Xb + (size_t)i * 4) = ov;
        }
    } else {
        int wb = vb - (NCH + 3125);
        if (wb < 4) {
            const float* W = wb == 0 ? p.w0a : wb == 1 ? p.w0b : wb == 2 ? p.w1a : p.w1b;
            short* Wt = wb == 0 ? p.Wt0a : wb == 1 ? p.Wt0b : wb == 2 ? p.Wt1a : p.Wt1b;
            for (int e = t; e < 4096; e += 256) {
                int k = e >> 6, n = e & 63;
                Wt[n * 64 + k] = f2bs(W[e]);
            }
        } else {
            for (int e = t; e < 8192; e += 256) {
                int k = e >> 6, n = e & 63;
                p.Wtf[n * 128 + k] = f2bs(p.lw[e]);
            }
        }
    }
}

__device__ __forceinline__ void stage_scan(int t, SMem& u, const P& p) {
    int v = 0;
    for (int c = 0; c < NCH; c++) v += p.part[c * 256 + t];
    u.scan_s[t] = v;
    __syncthreads();
    for (int d = 1; d < 256; d <<= 1) {
        int uu = (t >= d) ? u.scan_s[t - d] : 0;
        __syncthreads();
        u.scan_s[t] += uu;
        __syncthreads();
    }
    int ex = u.scan_s[t] - v;
    p.bbase[t] = ex;
    p.bres[t] = ex;
    if (t == 0) { p.bbase[256] = NE; p.off[NN] = NE; }
    p.sums[t] = 0.f;
    p.sums[256 + t] = 0.f;
}

__device__ __forceinline__ void stage_scatter(int vb, int t, SMem& u, const P& p) {
    __syncthreads();
    u.sca.cnt[t] = 0;
    __syncthreads();
    int base = vb * CHUNK;
    int n = NE - base; if (n > CHUNK) n = CHUNK;
    for (int i = t; i < n; i += 256) atomicAdd(&u.sca.cnt[p.dst[base + i] >> 8], 1);
    __syncthreads();
    u.sca.sc[t] = u.sca.cnt[t];
    __syncthreads();
    for (int d = 1; d < 256; d <<= 1) {
        int uu = (t >= d) ? u.sca.sc[t - d] : 0;
        __syncthreads();
        u.sca.sc[t] += uu;
        __syncthreads();
    }
    u.sca.loff[t] = u.sca.sc[t] - u.sca.cnt[t];
    u.sca.lcur[t] = u.sca.loff[t];
    __syncthreads();
    for (int i = t; i < n; i += 256) {
        int d = p.dst[base + i];
        int bk = d >> 8;
        int pos = atomicAdd(&u.sca.lcur[bk], 1);
        u.sca.packed[pos] = p.src[base + i] | ((d & 255) << 16) | (bk << 24);
    }
    __syncthreads();
    if (u.sca.cnt[t]) u.sca.gst[t] = atomicAdd(&p.bres[t], u.sca.cnt[t]);
    __syncthreads();
    for (int i = t; i < n; i += 256) {
        int v = u.sca.packed[i];
        int bk = (v >> 24) & 255;
        p.ebuf[u.sca.gst[bk] + i - u.sca.loff[bk]] = v & 0xFFFFFF;
    }
    __syncthreads();
}

__device__ __forceinline__ void stage_csr(int vb, int t, SMem& u, const P& p) {
    __syncthreads();
    int s0 = p.bbase[vb], s1 = p.bbase[vb + 1];
    int n = s1 - s0;
    u.sca.cnt[t] = 0;
    __syncthreads();
    for (int i = t; i < n; i += 256) atomicAdd(&u.sca.cnt[(p.ebuf[s0 + i] >> 16) & 255], 1);
    __syncthreads();
    u.sca.sc[t] = u.sca.cnt[t];
    __syncthreads();
    for (int d = 1; d < 256; d <<= 1) {
        int uu = (t >= d) ? u.sca.sc[t - d] : 0;
        __syncthreads();
        u.sca.sc[t] += uu;
        __syncthreads();
    }
    u.sca.loff[t] = u.sca.sc[t] - u.sca.cnt[t];
    u.sca.lcur[t] = u.sca.loff[t];
    int node = vb * 256 + t;
    if (node < NN) p.off[node] = s0 + u.sca.loff[t];
    __syncthreads();
    for (int i = t; i < n; i += 256) {
        int v = p.ebuf[s0 + i];
        int pos = atomicAdd(&u.sca.lcur[(v >> 16) & 255], 1);
        p.adj[s0 + pos] = v & 0xFFFF;
    }
    __syncthreads();
}

__device__ __forceinline__ float gather_row(const __hip_bfloat16* __restrict__ X,
                                            int lane, const int* __restrict__ off,
                                            const int* __restrict__ adj, int node) {
    float acc = bf2f(X[(size_t)node * 64 + lane]);
    int s = off[node], e = off[node + 1];
    int p = s;
    for (; p + 8 <= e; p += 8) {
        int j0 = adj[p + 0], j1 = adj[p + 1], j2 = adj[p + 2], j3 = adj[p + 3];
        int j4 = adj[p + 4], j5 = adj[p + 5], j6 = adj[p + 6], j7 = adj[p + 7];
        float v0 = bf2f(X[(size_t)j0 * 64 + lane]);
        float v1 = bf2f(X[(size_t)j1 * 64 + lane]);
        float v2 = bf2f(X[(size_t)j2 * 64 + lane]);
        float v3 = bf2f(X[(size_t)j3 * 64 + lane]);
        float v4 = bf2f(X[(size_t)j4 * 64 + lane]);
        float v5 = bf2f(X[(size_t)j5 * 64 + lane]);
        float v6 = bf2f(X[(size_t)j6 * 64 + lane]);
        float v7 = bf2f(X[(size_t)j7 * 64 + lane]);
        acc += ((v0 + v1) + (v2 + v3)) + ((v4 + v5) + (v6 + v7));
    }
    if (p + 4 <= e) {
        int j0 = adj[p + 0], j1 = adj[p + 1], j2 = adj[p + 2], j3 = adj[p + 3];
        float v0 = bf2f(X[(size_t)j0 * 64 + lane]);
        float v1 = bf2f(X[(size_t)j1 * 64 + lane]);
        float v2 = bf2f(X[(size_t)j2 * 64 + lane]);
        float v3 = bf2f(X[(size_t)j3 * 64 + lane]);
        acc += (v0 + v1) + (v2 + v3);
        p += 4;
    }
    for (; p < e; p++) acc += bf2f(X[(size_t)adj[p] * 64 + lane]);
    return acc;
}

__device__ __forceinline__ void bn_coeff(int t, const float* __restrict__ stats,
                                         const float* __restrict__ g,
                                         const float* __restrict__ be,
                                         float* sc, float* sh) {
    if (t < 64) {
        float m = stats[t] * (1.0f / NN);
        float var = stats[64 + t] * (1.0f / NN) - m * m;
        if (var < 0.f) var = 0.f;
        float s = g[t] * rsqrtf(var + BN_EPS);
        sc[t] = s;
        sh[t] = be[t] - m * s;
    }
}

__device__ __forceinline__ void stage_gemm_a(int B, int t, const __hip_bfloat16* Ab,
                                             const short* Wt, const float* bias,
                                             float* T, float* sums, SMem& u) {
    __syncthreads();
    if (t < 64) { u.bn.lsum[t] = 0.f; u.bn.lssq[t] = 0.f; }
    __syncthreads();
    int wv = t >> 6, L = t & 63;
    int m = L & 15, quad = L >> 4;
    int wrow = B * 64 + wv * 16;
    int arow = wrow + m;
    if (arow >= NN) arow = NN - 1;
    const short* Ap = (const short*)Ab;
    s16x8 a0 = *(const s16x8*)(Ap + (size_t)arow * 64 + quad * 8);
    s16x8 a1 = *(const s16x8*)(Ap + (size_t)arow * 64 + 32 + quad * 8);
    f32x4 acc[4];
    #pragma unroll
    for (int nt = 0; nt < 4; nt++) {
        int n = nt * 16 + m;
        s16x8 b0 = *(const s16x8*)(Wt + n * 64 + quad * 8);
        s16x8 b1 = *(const s16x8*)(Wt + n * 64 + 32 + quad * 8);
        acc[nt] = (f32x4){0.f, 0.f, 0.f, 0.f};
        acc[nt] = __builtin_amdgcn_mfma_f32_16x16x32_bf16(a0, b0, acc[nt], 0, 0, 0);
        acc[nt] = __builtin_amdgcn_mfma_f32_16x16x32_bf16(a1, b1, acc[nt], 0, 0, 0);
    }
    #pragma unroll
    for (int nt = 0; nt < 4; nt++) {
        int col = nt * 16 + m;
        float bv = bias[col];
        float ps = 0.f, pq = 0.f;
        #pragma unroll
        for (int r = 0; r < 4; r++) {
            int orow = wrow + quad * 4 + r;
            if (orow < NN) {
                float v = acc[nt][r] + bv;
                T[(size_t)orow * 64 + col] = v;
                ps += v;
                pq += v * v;
            }
        }
        atomicAdd(&u.bn.lsum[col], ps);
        atomicAdd(&u.bn.lssq[col], pq);
    }
    __syncthreads();
    if (t < 64) {
        atomicAdd(&sums[t], u.bn.lsum[t]);
        atomicAdd(&sums[64 + t], u.bn.lssq[t]);
    }
}

__device__ __forceinline__ void stage_gemm_bn(int B, int t, const float* Tin,
                                              const float* stats, const float* g,
                                              const float* be, const short* Wt,
                                              const float* bias, float* T, float* sums,
                                              SMem& u) {
    __syncthreads();
    bn_coeff(t, stats, g, be, u.bn.sc, u.bn.sh);
    if (t < 64) { u.bn.lsum[t] = 0.f; u.bn.lssq[t] = 0.f; }
    __syncthreads();
    int wv = t >> 6, L = t & 63;
    int m = L & 15, quad = L >> 4;
    int wrow = B * 64 + wv * 16;
    int arow = wrow + m;
    if (arow >= NN) arow = NN - 1;
    f32x4 t0 = *(const f32x4*)(Tin + (size_t)arow * 64 + quad * 8);
    f32x4 t1 = *(const f32x4*)(Tin + (size_t)arow * 64 + quad * 8 + 4);
    f32x4 t2 = *(const f32x4*)(Tin + (size_t)arow * 64 + 32 + quad * 8);
    f32x4 t3 = *(const f32x4*)(Tin + (size_t)arow * 64 + 32 + quad * 8 + 4);
    s16x8 a0, a1;
    #pragma unroll
    for (int j = 0; j < 4; j++) {
        int k0 = quad * 8 + j, k1 = quad * 8 + 4 + j;
        float u0 = t0[j] * u.bn.sc[k0] + u.bn.sh[k0]; a0[j]     = f2bs(u0 > 0.f ? u0 : 0.f);
        float u1 = t1[j] * u.bn.sc[k1] + u.bn.sh[k1]; a0[4 + j] = f2bs(u1 > 0.f ? u1 : 0.f);
        float u2 = t2[j] * u.bn.sc[32 + k0] + u.bn.sh[32 + k0]; a1[j]     = f2bs(u2 > 0.f ? u2 : 0.f);
        float u3 = t3[j] * u.bn.sc[32 + k1] + u.bn.sh[32 + k1]; a1[4 + j] = f2bs(u3 > 0.f ? u3 : 0.f);
    }
    f32x4 acc[4];
    #pragma unroll
    for (int nt = 0; nt < 4; nt++) {
        int n = nt * 16 + m;
        s16x8 b0 = *(const s16x8*)(Wt + n * 64 + quad * 8);
        s16x8 b1 = *(const s16x8*)(Wt + n * 64 + 32 + quad * 8);
        acc[nt] = (f32x4){0.f, 0.f, 0.f, 0.f};
        acc[nt] = __builtin_amdgcn_mfma_f32_16x16x32_bf16(a0, b0, acc[nt], 0, 0, 0);
        acc[nt] = __builtin_amdgcn_mfma_f32_16x16x32_bf16(a1, b1, acc[nt], 0, 0, 0);
    }
    #pragma unroll
    for (int nt = 0; nt < 4; nt++) {
        int col = nt * 16 + m;
        float bv = bias[col];
        float ps = 0.f, pq = 0.f;
        #pragma unroll
        for (int r = 0; r < 4; r++) {
            int orow = wrow + quad * 4 + r;
            if (orow < NN) {
                float v = acc[nt][r] + bv;
                T[(size_t)orow * 64 + col] = v;
                ps += v;
                pq += v * v;
            }
        }
        atomicAdd(&u.bn.lsum[col], ps);
        atomicAdd(&u.bn.lssq[col], pq);
    }
    __syncthreads();
    if (t < 64) {
        atomicAdd(&sums[t], u.bn.lsum[t]);
        atomicAdd(&sums[64 + t], u.bn.lssq[t]);
    }
}

__device__ __forceinline__ void stage_fin(int B, int t, SMem& u, const P& p) {
    // u.bn.sc/sh must already hold the h2 BN coefficients
    int wv = t >> 6, L = t & 63;
    int m = L & 15, quad = L >> 4;
    int wrow = B * 64 + wv * 16;
    int arow = wrow + m;
    if (arow >= NN) arow = NN - 1;
    const short* Hp = (const short*)p.HCb;
    s16x8 a0 = *(const s16x8*)(Hp + (size_t)arow * 64 + quad * 8);
    s16x8 a1 = *(const s16x8*)(Hp + (size_t)arow * 64 + 32 + quad * 8);
    f32x4 t0 = *(const f32x4*)(p.T2 + (size_t)arow * 64 + quad * 8);
    f32x4 t1 = *(const f32x4*)(p.T2 + (size_t)arow * 64 + quad * 8 + 4);
    f32x4 t2 = *(const f32x4*)(p.T2 + (size_t)arow * 64 + 32 + quad * 8);
    f32x4 t3 = *(const f32x4*)(p.T2 + (size_t)arow * 64 + 32 + quad * 8 + 4);
    s16x8 a2, a3;
    #pragma unroll
    for (int j = 0; j < 4; j++) {
        int k0 = quad * 8 + j, k1 = quad * 8 + 4 + j;
        float u0 = t0[j] * u.bn.sc[k0] + u.bn.sh[k0]; a2[j]     = f2bs(u0 > 0.f ? u0 : 0.f);
        float u1 = t1[j] * u.bn.sc[k1] + u.bn.sh[k1]; a2[4 + j] = f2bs(u1 > 0.f ? u1 : 0.f);
        float u2 = t2[j] * u.bn.sc[32 + k0] + u.bn.sh[32 + k0]; a3[j]     = f2bs(u2 > 0.f ? u2 : 0.f);
        float u3 = t3[j] * u.bn.sc[32 + k1] + u.bn.sh[32 + k1]; a3[4 + j] = f2bs(u3 > 0.f ? u3 : 0.f);
    }
    f32x4 acc[4];
    #pragma unroll
    for (int nt = 0; nt < 4; nt++) {
        int n = nt * 16 + m;
        s16x8 b0 = *(const s16x8*)(p.Wtf + n * 128 + quad * 8);
        s16x8 b1 = *(const s16x8*)(p.Wtf + n * 128 + 32 + quad * 8);
        s16x8 b2 = *(const s16x8*)(p.Wtf + n * 128 + 64 + quad * 8);
        s16x8 b3 = *(const s16x8*)(p.Wtf + n * 128 + 96 + quad * 8);
        acc[nt] = (f32x4){0.f, 0.f, 0.f, 0.f};
        acc[nt] = __builtin_amdgcn_mfma_f32_16x16x32_bf16(a0, b0, acc[nt], 0, 0, 0);
        acc[nt] = __builtin_amdgcn_mfma_f32_16x16x32_bf16(a1, b1, acc[nt], 0, 0, 0);
        acc[nt] = __builtin_amdgcn_mfma_f32_16x16x32_bf16(a2, b2, acc[nt], 0, 0, 0);
        acc[nt] = __builtin_amdgcn_mfma_f32_16x16x32_bf16(a3, b3, acc[nt], 0, 0, 0);
    }
    #pragma unroll
    for (int nt = 0; nt < 4; nt++) {
        int col = nt * 16 + m;
        float bv = p.lb[col];
        #pragma unroll
        for (int r = 0; r < 4; r++) {
            int orow = wrow + quad * 4 + r;
            if (orow < NN) p.out[(size_t)orow * 64 + col] = acc[nt][r] + bv;
        }
    }
}

// ================= fused cooperative kernel =================
__global__ void __launch_bounds__(256) fused_k(P p) {
    cg::grid_group grid = cg::this_grid();
    __shared__ SMem u;
    int B = blockIdx.x, t = threadIdx.x, G = gridDim.x;
    int lane = t & 63, wv = t >> 6;

    for (int vb = B; vb < PREPV; vb += G) stage_prep(vb, t, u, p);
    grid.sync();
    if (B == 0) stage_scan(t, u, p);
    grid.sync();
    for (int vb = B; vb < NCH; vb += G) stage_scatter(vb, t, u, p);
    grid.sync();
    for (int vb = B; vb < NCH; vb += G) stage_csr(vb, t, u, p);
    grid.sync();
    for (int vb = B; vb < 12500; vb += G) {
        int node = vb * 4 + wv;
        if (node < NN) {
            float acc = gather_row(p.Xb, lane, p.off, p.adj, node);
            p.AGGb[(size_t)node * 64 + lane] = __float2bfloat16(acc);
        }
    }
    grid.sync();
    for (int vb = B; vb < MGRID; vb += G)
        stage_gemm_a(vb, t, p.AGGb, p.Wt0a, p.b0a, p.T, p.sums + 0, u);
    grid.sync();
    for (int vb = B; vb < MGRID; vb += G)
        stage_gemm_bn(vb, t, p.T, p.sums + 0, p.g0a, p.be0a, p.Wt0b, p.b0b,
                      p.T2, p.sums + 128, u);
    grid.sync();
    __syncthreads();
    bn_coeff(t, p.sums + 128, p.g0b, p.be0b, u.bn.sc, u.bn.sh);
    __syncthreads();
    for (int vb = B; vb < 3125; vb += G) {
        int i = vb * 256 + t;
        if (i < NN * 16) {
            int row = i >> 4, f = (i & 15) * 4;
            f32x4 v = *(const f32x4*)(p.T2 + (size_t)row * 64 + f);
            s16x4 ub;
            #pragma unroll
            for (int j = 0; j < 4; j++) {
                float w = v[j] * u.bn.sc[f + j] + u.bn.sh[f + j];
                ub[j] = f2bs(w > 0.f ? w : 0.f);
            }
            *(s16x4*)((short*)p.HCb + (size_t)row * 64 + f) = ub;
        }
    }
    grid.sync();
    for (int vb = B; vb < 12500; vb += G) {
        int node = vb * 4 + wv;
        if (node < NN) {
            float acc = gather_row(p.HCb, lane, p.off, p.adj, node);
            p.AGGb[(size_t)node * 64 + lane] = __float2bfloat16(acc);
        }
    }
    grid.sync();
    for (int vb = B; vb < MGRID; vb += G)
        stage_gemm_a(vb, t, p.AGGb, p.Wt1a, p.b1a, p.T, p.sums + 256, u);
    grid.sync();
    for (int vb = B; vb < MGRID; vb += G)
        stage_gemm_bn(vb, t, p.T, p.sums + 256, p.g1a, p.be1a, p.Wt1b, p.b1b,
                      p.T2, p.sums + 384, u);
    grid.sync();
    __syncthreads();
    bn_coeff(t, p.sums + 384, p.g1b, p.be1b, u.bn.sc, u.bn.sh);
    __syncthreads();
    for (int vb = B; vb < MGRID; vb += G) stage_fin(vb, t, u, p);
}

// ================= fallback wrappers (used only if coop launch fails) ==========
__global__ void prep_w(P p)  { __shared__ SMem u; stage_prep(blockIdx.x, threadIdx.x, u, p); }
__global__ void scan_w(P p)  { __shared__ SMem u; stage_scan(threadIdx.x, u, p); }
__global__ void scat_w(P p)  { __shared__ SMem u; stage_scatter(blockIdx.x, threadIdx.x, u, p); }
__global__ void csrb_w(P p)  { __shared__ SMem u; stage_csr(blockIdx.x, threadIdx.x, u, p); }
__global__ void gath_w(P p, int layer) {
    int node = blockIdx.x * 4 + (threadIdx.x >> 6);
    int lane = threadIdx.x & 63;
    if (node >= NN) return;
    const __hip_bfloat16* X = layer == 0 ? p.Xb : p.HCb;
    float acc = gather_row(X, lane, p.off, p.adj, node);
    p.AGGb[(size_t)node * 64 + lane] = __float2bfloat16(acc);
}
__global__ void gemma_w(P p, int layer) {
    __shared__ SMem u;
    if (layer == 0) stage_gemm_a(blockIdx.x, threadIdx.x, p.AGGb, p.Wt0a, p.b0a, p.T, p.sums + 0, u);
    else            stage_gemm_a(blockIdx.x, threadIdx.x, p.AGGb, p.Wt1a, p.b1a, p.T, p.sums + 256, u);
}
__global__ void gemmbn_w(P p, int layer) {
    __shared__ SMem u;
    if (layer == 0) stage_gemm_bn(blockIdx.x, threadIdx.x, p.T, p.sums + 0, p.g0a, p.be0a,
                                  p.Wt0b, p.b0b, p.T2, p.sums + 128, u);
    else            stage_gemm_bn(blockIdx.x, threadIdx.x, p.T, p.sums + 256, p.g1a, p.be1a,
                                  p.Wt1b, p.b1b, p.T2, p.sums + 384, u);
}
__global__ void bnfin_w(P p) {
    __shared__ SMem u;
    int t = threadIdx.x;
    bn_coeff(t, p.sums + 128, p.g0b, p.be0b, u.bn.sc, u.bn.sh);
    __syncthreads();
    int i = blockIdx.x * 256 + t;
    if (i < NN * 16) {
        int row = i >> 4, f = (i & 15) * 4;
        f32x4 v = *(const f32x4*)(p.T2 + (size_t)row * 64 + f);
        s16x4 ub;
        #pragma unroll
        for (int j = 0; j < 4; j++) {
            float w = v[j] * u.bn.sc[f + j] + u.bn.sh[f + j];
            ub[j] = f2bs(w > 0.f ? w : 0.f);
        }
        *(s16x4*)((short*)p.HCb + (size_t)row * 64 + f) = ub;
    }
}
__global__ void fin_w(P p) {
    __shared__ SMem u;
    int t = threadIdx.x;
    bn_coeff(t, p.sums + 384, p.g1b, p.be1b, u.bn.sc, u.bn.sh);
    __syncthreads();
    stage_fin(blockIdx.x, t, u, p);
}

// ---------------- launch ----------------
extern "C" void kernel_launch(void* const* d_in, const int* in_sizes, int n_in,
                              void* d_out, int out_size, void* d_ws, size_t ws_size,
                              hipStream_t stream) {
    (void)in_sizes; (void)n_in; (void)out_size; (void)ws_size;
    const int* ei = (const int*)d_in[1];

    char* wsb = (char*)d_ws;
    size_t o = 0;
    auto alloc = [&](size_t bytes) -> char* {
        char* ptr = wsb + o;
        o += (bytes + 255) & ~(size_t)255;
        return ptr;
    };

    P p;
    p.src = ei;
    p.dst = ei + NE;
    p.part  = (int*)alloc(NCH * 256 * 4);
    p.sums  = (float*)alloc(512 * 4);
    p.bbase = (int*)alloc(257 * 4);
    p.bres  = (int*)alloc(256 * 4);
    p.off   = (int*)alloc((NN + 1) * 4);
    p.adj   = (int*)alloc(NE * 4);
    p.ebuf  = (int*)alloc(NE * 4);
    p.Xb    = (__hip_bfloat16*)alloc((size_t)NN * 64 * 2);
    p.AGGb  = (__hip_bfloat16*)alloc((size_t)NN * 64 * 2);
    p.HCb   = (__hip_bfloat16*)alloc((size_t)NN * 64 * 2);
    p.T     = (float*)alloc((size_t)NN * 64 * 4);
    p.T2    = (float*)alloc((size_t)NN * 64 * 4);
    p.Wt0a  = (short*)alloc(4096 * 2);
    p.Wt0b  = (short*)alloc(4096 * 2);
    p.Wt1a  = (short*)alloc(4096 * 2);
    p.Wt1b  = (short*)alloc(4096 * 2);
    p.Wtf   = (short*)alloc(8192 * 2);

    p.x   = (const float*)d_in[0];
    p.w0a = (const float*)d_in[2];  p.b0a = (const float*)d_in[3];
    p.g0a = (const float*)d_in[4];  p.be0a = (const float*)d_in[5];
    p.w0b = (const float*)d_in[6];  p.b0b = (const float*)d_in[7];
    p.g0b = (const float*)d_in[8];  p.be0b = (const float*)d_in[9];
    p.w1a = (const float*)d_in[10]; p.b1a = (const float*)d_in[11];
    p.g1a = (const float*)d_in[12]; p.be1a = (const float*)d_in[13];
    p.w1b = (const float*)d_in[14]; p.b1b = (const float*)d_in[15];
    p.g1b = (const float*)d_in[16]; p.be1b = (const float*)d_in[17];
    p.lw  = (const float*)d_in[18]; p.lb = (const float*)d_in[19];
    p.out = (float*)d_out;

    // size the cooperative grid from actual occupancy (LDS 21.25KB + VGPR 68
    // both predict 7 blocks/CU -> 1792); clamp to [GRID_MIN, GRID_MAX]
    int nb = 0;
    hipError_t qerr = hipOccupancyMaxActiveBlocksPerMultiprocessor(
        &nb, reinterpret_cast<const void*>(fused_k), 256, 0);
    int grid = (qerr == hipSuccess && nb > 0) ? nb * 256 : GRID_MIN;
    if (grid > GRID_MAX) grid = GRID_MAX;
    if (grid < GRID_MIN) grid = GRID_MIN;

    void* args[] = { &p };
    hipError_t err = hipLaunchCooperativeKernel(reinterpret_cast<void*>(fused_k),
                                                dim3(grid), dim3(256), args, 0, stream);
    if (err != hipSuccess && grid != GRID_MIN) {
        (void)hipGetLastError();
        err = hipLaunchCooperativeKernel(reinterpret_cast<void*>(fused_k),
                                         dim3(GRID_MIN), dim3(256), args, 0, stream);
    }
    if (err != hipSuccess) {
        (void)hipGetLastError();  // clear sticky error; fall back to multi-kernel path
        prep_w  <<<PREPV, 256, 0, stream>>>(p);
        scan_w  <<<1,     256, 0, stream>>>(p);
        scat_w  <<<NCH,   256, 0, stream>>>(p);
        csrb_w  <<<NCH,   256, 0, stream>>>(p);
        gath_w  <<<12500, 256, 0, stream>>>(p, 0);
        gemma_w <<<MGRID, 256, 0, stream>>>(p, 0);
        gemmbn_w<<<MGRID, 256, 0, stream>>>(p, 0);
        bnfin_w <<<3125,  256, 0, stream>>>(p);
        gath_w  <<<12500, 256, 0, stream>>>(p, 1);
        gemma_w <<<MGRID, 256, 0, stream>>>(p, 1);
        gemmbn_w<<<MGRID, 256, 0, stream>>>(p, 1);
        fin_w   <<<MGRID, 256, 0, stream>>>(p);
    }
}

// Round 13
// 321.972 us; speedup vs baseline: 3.0413x; 3.0230x over previous
//
#include <hip/hip_runtime.h>
#include <hip/hip_bf16.h>

#define NN 50000
#define NE 800000
#define BN_EPS 1e-5f
#define CHUNK 4096
#define NCH 196    // ceil(NE / CHUNK) = 196 (196*4096 = 802816)
#define NBK 196    // ceil(NN / 256) dst-buckets

typedef __attribute__((ext_vector_type(4))) float f32x4;
typedef __attribute__((ext_vector_type(8))) short s16x8;   // 8 bf16 = MFMA A/B frag
typedef __attribute__((ext_vector_type(4))) short s16x4;

__device__ __forceinline__ float bf2f(__hip_bfloat16 v) { return __bfloat162float(v); }
__device__ __forceinline__ float bs2f(short v) {
    unsigned u = ((unsigned)(unsigned short)v) << 16;
    return __builtin_bit_cast(float, u);
}
__device__ __forceinline__ short f2bs(float v) {
    __hip_bfloat16 b = __float2bfloat16(v);
    return __builtin_bit_cast(short, b);
}

// ---- prep: [0,196) bhist chunks -> part; [196,3321) cvt x->Xb; [3321,3326) W^T->bf16
__global__ void prep_k(const int* __restrict__ dst, int* __restrict__ part,
                       const float* __restrict__ x, __hip_bfloat16* __restrict__ Xb,
                       const float* __restrict__ w0a, const float* __restrict__ w0b,
                       const float* __restrict__ w1a, const float* __restrict__ w1b,
                       const float* __restrict__ lw,
                       short* __restrict__ Wt0a, short* __restrict__ Wt0b,
                       short* __restrict__ Wt1a, short* __restrict__ Wt1b,
                       short* __restrict__ Wtf) {
    int b = blockIdx.x, t = threadIdx.x;
    if (b < NCH) {
        __shared__ int c[256];
        c[t] = 0;
        __syncthreads();
        int base = b * CHUNK;
        int n = NE - base; if (n > CHUNK) n = CHUNK;
        for (int i = t; i < n; i += 256) atomicAdd(&c[dst[base + i] >> 8], 1);
        __syncthreads();
        part[b * 256 + t] = c[t];
    } else if (b < 196 + 3125) {
        int i = (b - 196) * 256 + t;  // over NN*16 = 800000 float4s
        if (i < NN * 16) {
            f32x4 v = *(const f32x4*)(x + (size_t)i * 4);
            s16x4 ov;
            #pragma unroll
            for (int j = 0; j < 4; j++) ov[j] = f2bs(v[j]);
            *(s16x4*)((short*)Xb + (size_t)i * 4) = ov;
        }
    } else {
        int wb = b - 3321;
        if (wb < 4) {
            const float* W = wb == 0 ? w0a : wb == 1 ? w0b : wb == 2 ? w1a : w1b;
            short* Wt = wb == 0 ? Wt0a : wb == 1 ? Wt0b : wb == 2 ? Wt1a : Wt1b;
            for (int e = t; e < 4096; e += 256) {
                int k = e >> 6, n = e & 63;
                Wt[n * 64 + k] = f2bs(W[e]);
            }
        } else {
            for (int e = t; e < 8192; e += 256) {
                int k = e >> 6, n = e & 63;
                Wtf[n * 128 + k] = f2bs(lw[e]);
            }
        }
    }
}

// ---- scan bucket totals (sum part over chunks) -> bbase/bres; zero sums -------
__global__ void bscan_k(const int* __restrict__ part, int* __restrict__ bbase,
                        int* __restrict__ bres, int* __restrict__ off,
                        float* __restrict__ sums) {
    __shared__ int s[256];
    int t = threadIdx.x;
    int v = 0;
    for (int c = 0; c < NCH; c++) v += part[c * 256 + t];
    s[t] = v;
    __syncthreads();
    for (int d = 1; d < 256; d <<= 1) {
        int u = (t >= d) ? s[t - d] : 0;
        __syncthreads();
        s[t] += u;
        __syncthreads();
    }
    int ex = s[t] - v;
    bbase[t] = ex;
    bres[t] = ex;
    if (t == 0) { bbase[256] = NE; off[NN] = NE; }
    sums[t] = 0.f; sums[256 + t] = 0.f;  // 512 floats total
}

// ---- bucket scatter: chunk -> bucket-ordered ebuf (coalesced writes) ----------
// packed int: src (16b) | dst&255 (8b) | bucket (8b)
__global__ void bscatter_k(const int* __restrict__ src, const int* __restrict__ dst,
                           int* __restrict__ bres, int* __restrict__ ebuf) {
    __shared__ int cnt[256], loff[256], lcur[256], gst[256], sc[256];
    __shared__ int packed[CHUNK];
    int t = threadIdx.x;
    cnt[t] = 0;
    __syncthreads();
    int base = blockIdx.x * CHUNK;
    int n = NE - base; if (n > CHUNK) n = CHUNK;
    for (int i = t; i < n; i += 256) atomicAdd(&cnt[dst[base + i] >> 8], 1);
    __syncthreads();
    sc[t] = cnt[t];
    __syncthreads();
    for (int d = 1; d < 256; d <<= 1) {
        int u = (t >= d) ? sc[t - d] : 0;
        __syncthreads();
        sc[t] += u;
        __syncthreads();
    }
    loff[t] = sc[t] - cnt[t];
    lcur[t] = loff[t];
    __syncthreads();
    for (int i = t; i < n; i += 256) {
        int d = dst[base + i];
        int b = d >> 8;
        int p = atomicAdd(&lcur[b], 1);
        packed[p] = src[base + i] | ((d & 255) << 16) | (b << 24);
    }
    __syncthreads();
    if (cnt[t]) gst[t] = atomicAdd(&bres[t], cnt[t]);
    __syncthreads();
    for (int i = t; i < n; i += 256) {
        int v = packed[i];
        int b = (v >> 24) & 255;
        ebuf[gst[b] + i - loff[b]] = v & 0xFFFFFF;
    }
}

// ---- per-bucket CSR: off[] + adj[] --------------------------------------------
__global__ void csr_k(const int* __restrict__ bbase, const int* __restrict__ ebuf,
                      int* __restrict__ off, int* __restrict__ adj) {
    __shared__ int cnt[256], loff[256], lcur[256], sc[256];
    int b = blockIdx.x, t = threadIdx.x;
    int s0 = bbase[b], s1 = bbase[b + 1];
    int n = s1 - s0;
    cnt[t] = 0;
    __syncthreads();
    for (int i = t; i < n; i += 256) atomicAdd(&cnt[(ebuf[s0 + i] >> 16) & 255], 1);
    __syncthreads();
    sc[t] = cnt[t];
    __syncthreads();
    for (int d = 1; d < 256; d <<= 1) {
        int u = (t >= d) ? sc[t - d] : 0;
        __syncthreads();
        sc[t] += u;
        __syncthreads();
    }
    loff[t] = sc[t] - cnt[t];
    lcur[t] = loff[t];
    int node = b * 256 + t;
    if (node < NN) off[node] = s0 + loff[t];
    __syncthreads();
    for (int i = t; i < n; i += 256) {
        int v = ebuf[s0 + i];
        int p = atomicAdd(&lcur[(v >> 16) & 255], 1);
        adj[s0 + p] = v & 0xFFFF;
    }
}

// ---- FUSED gather + MFMA GEMM + bias + BN stats -> T fp32 ---------------------
// wave = 16 nodes x 64 cols. Lane L serves node m=(L&15), features
// [quad*8, quad*8+8) and [32+quad*8, ...): gathers its own A-fragment slice in
// registers (fp32), converts to bf16 a-frags, then MFMA. No LDS A-tile ->
// high occupancy (the round-7 LDS-fused version died at 26% occ).
__global__ void ggemm_k(const __hip_bfloat16* __restrict__ X,
                        const int* __restrict__ off, const int* __restrict__ adj,
                        const short* __restrict__ Wt,    // 64x64 bf16, [n][k]
                        const float* __restrict__ bias,
                        float* __restrict__ T,
                        float* __restrict__ sums) {
    __shared__ float lsum[64], lssq[64];
    int t = threadIdx.x;
    if (t < 64) { lsum[t] = 0.f; lssq[t] = 0.f; }
    __syncthreads();
    int wv = t >> 6, L = t & 63;
    int m = L & 15, quad = L >> 4;
    int wrow = blockIdx.x * 64 + wv * 16;
    int node = wrow + m;
    if (node >= NN) node = NN - 1;  // dup row; stores/stats guarded below
    const short* Xp = (const short*)X;

    // self row slice
    const short* rp = Xp + (size_t)node * 64 + quad * 8;
    s16x8 sl = *(const s16x8*)rp;
    s16x8 sh = *(const s16x8*)(rp + 32);
    float aL[8], aH[8];
    #pragma unroll
    for (int j = 0; j < 8; j++) { aL[j] = bs2f(sl[j]); aH[j] = bs2f(sh[j]); }

    // neighbors: lanes sharing node m read the same adj entries (broadcast);
    // 4-deep edge pipelining = 8 independent 16B loads in flight per lane
    int s = off[node], e = off[node + 1];
    int p = s;
    for (; p + 4 <= e; p += 4) {
        int j0 = adj[p], j1 = adj[p + 1], j2 = adj[p + 2], j3 = adj[p + 3];
        const short* r0 = Xp + (size_t)j0 * 64 + quad * 8;
        const short* r1 = Xp + (size_t)j1 * 64 + quad * 8;
        const short* r2 = Xp + (size_t)j2 * 64 + quad * 8;
        const short* r3 = Xp + (size_t)j3 * 64 + quad * 8;
        s16x8 v0 = *(const s16x8*)r0, w0 = *(const s16x8*)(r0 + 32);
        s16x8 v1 = *(const s16x8*)r1, w1 = *(const s16x8*)(r1 + 32);
        s16x8 v2 = *(const s16x8*)r2, w2 = *(const s16x8*)(r2 + 32);
        s16x8 v3 = *(const s16x8*)r3, w3 = *(const s16x8*)(r3 + 32);
        #pragma unroll
        for (int j = 0; j < 8; j++) {
            aL[j] += (bs2f(v0[j]) + bs2f(v1[j])) + (bs2f(v2[j]) + bs2f(v3[j]));
            aH[j] += (bs2f(w0[j]) + bs2f(w1[j])) + (bs2f(w2[j]) + bs2f(w3[j]));
        }
    }
    for (; p < e; p++) {
        int j0 = adj[p];
        const short* r0 = Xp + (size_t)j0 * 64 + quad * 8;
        s16x8 v0 = *(const s16x8*)r0, w0 = *(const s16x8*)(r0 + 32);
        #pragma unroll
        for (int j = 0; j < 8; j++) { aL[j] += bs2f(v0[j]); aH[j] += bs2f(w0[j]); }
    }

    s16x8 a0, a1;
    #pragma unroll
    for (int j = 0; j < 8; j++) { a0[j] = f2bs(aL[j]); a1[j] = f2bs(aH[j]); }

    f32x4 acc[4];
    #pragma unroll
    for (int nt = 0; nt < 4; nt++) {
        int n = nt * 16 + m;
        s16x8 b0 = *(const s16x8*)(Wt + n * 64 + quad * 8);
        s16x8 b1 = *(const s16x8*)(Wt + n * 64 + 32 + quad * 8);
        acc[nt] = (f32x4){0.f, 0.f, 0.f, 0.f};
        acc[nt] = __builtin_amdgcn_mfma_f32_16x16x32_bf16(a0, b0, acc[nt], 0, 0, 0);
        acc[nt] = __builtin_amdgcn_mfma_f32_16x16x32_bf16(a1, b1, acc[nt], 0, 0, 0);
    }
    #pragma unroll
    for (int nt = 0; nt < 4; nt++) {
        int col = nt * 16 + m;
        float bv = bias[col];
        float ps = 0.f, pq = 0.f;
        #pragma unroll
        for (int r = 0; r < 4; r++) {
            int orow = wrow + quad * 4 + r;
            if (orow < NN) {
                float v = acc[nt][r] + bv;
                T[(size_t)orow * 64 + col] = v;
                ps += v;
                pq += v * v;
            }
        }
        atomicAdd(&lsum[col], ps);
        atomicAdd(&lssq[col], pq);
    }
    __syncthreads();
    if (t < 64) {
        atomicAdd(&sums[t], lsum[t]);
        atomicAdd(&sums[64 + t], lssq[t]);
    }
}

// ---- GEMM with A = relu(bn(T)) built on the fly -> Tout fp32 + stats ----------
__global__ void gemm_bn_k(const float* __restrict__ Tin,
                          const float* __restrict__ stats,
                          const float* __restrict__ g, const float* __restrict__ be,
                          const short* __restrict__ Wt,    // 64x64 bf16 [n][k]
                          const float* __restrict__ bias,
                          float* __restrict__ T,
                          float* __restrict__ sums) {
    __shared__ float sc[64], sh[64], lsum[64], lssq[64];
    int tid = threadIdx.x;
    if (tid < 64) {
        float mm = stats[tid] * (1.0f / NN);
        float var = stats[64 + tid] * (1.0f / NN) - mm * mm;
        if (var < 0.f) var = 0.f;
        float s = g[tid] * rsqrtf(var + BN_EPS);
        sc[tid] = s;
        sh[tid] = be[tid] - mm * s;
        lsum[tid] = 0.f; lssq[tid] = 0.f;
    }
    __syncthreads();
    int wv = tid >> 6, L = tid & 63;
    int m = L & 15, quad = L >> 4;
    int wrow = blockIdx.x * 64 + wv * 16;
    int arow = wrow + m;
    if (arow >= NN) arow = NN - 1;
    f32x4 t0 = *(const f32x4*)(Tin + (size_t)arow * 64 + quad * 8);
    f32x4 t1 = *(const f32x4*)(Tin + (size_t)arow * 64 + quad * 8 + 4);
    f32x4 t2 = *(const f32x4*)(Tin + (size_t)arow * 64 + 32 + quad * 8);
    f32x4 t3 = *(const f32x4*)(Tin + (size_t)arow * 64 + 32 + quad * 8 + 4);
    s16x8 a0, a1;
    #pragma unroll
    for (int j = 0; j < 4; j++) {
        int k0 = quad * 8 + j, k1 = quad * 8 + 4 + j;
        float u0 = t0[j] * sc[k0] + sh[k0]; a0[j]     = f2bs(u0 > 0.f ? u0 : 0.f);
        float u1 = t1[j] * sc[k1] + sh[k1]; a0[4 + j] = f2bs(u1 > 0.f ? u1 : 0.f);
        float u2 = t2[j] * sc[32 + k0] + sh[32 + k0]; a1[j]     = f2bs(u2 > 0.f ? u2 : 0.f);
        float u3 = t3[j] * sc[32 + k1] + sh[32 + k1]; a1[4 + j] = f2bs(u3 > 0.f ? u3 : 0.f);
    }
    f32x4 acc[4];
    #pragma unroll
    for (int nt = 0; nt < 4; nt++) {
        int n = nt * 16 + m;
        s16x8 b0 = *(const s16x8*)(Wt + n * 64 + quad * 8);
        s16x8 b1 = *(const s16x8*)(Wt + n * 64 + 32 + quad * 8);
        acc[nt] = (f32x4){0.f, 0.f, 0.f, 0.f};
        acc[nt] = __builtin_amdgcn_mfma_f32_16x16x32_bf16(a0, b0, acc[nt], 0, 0, 0);
        acc[nt] = __builtin_amdgcn_mfma_f32_16x16x32_bf16(a1, b1, acc[nt], 0, 0, 0);
    }
    #pragma unroll
    for (int nt = 0; nt < 4; nt++) {
        int col = nt * 16 + m;
        float bv = bias[col];
        float ps = 0.f, pq = 0.f;
        #pragma unroll
        for (int r = 0; r < 4; r++) {
            int orow = wrow + quad * 4 + r;
            if (orow < NN) {
                float v = acc[nt][r] + bv;
                T[(size_t)orow * 64 + col] = v;
                ps += v;
                pq += v * v;
            }
        }
        atomicAdd(&lsum[col], ps);
        atomicAdd(&lssq[col], pq);
    }
    __syncthreads();
    if (tid < 64) {
        atomicAdd(&sums[tid], lsum[tid]);
        atomicAdd(&sums[64 + tid], lssq[tid]);
    }
}

// ---- BN finalize + apply + ReLU: T2 fp32 -> HCb bf16 --------------------------
__global__ void bn_k(const float* __restrict__ T, const float* __restrict__ sums,
                     const float* __restrict__ g, const float* __restrict__ be,
                     __hip_bfloat16* __restrict__ Hb) {
    __shared__ float sc[64], sh[64];
    int tid = threadIdx.x;
    if (tid < 64) {
        float m = sums[tid] * (1.0f / NN);
        float var = sums[64 + tid] * (1.0f / NN) - m * m;
        if (var < 0.f) var = 0.f;
        float s = g[tid] * rsqrtf(var + BN_EPS);
        sc[tid] = s;
        sh[tid] = be[tid] - m * s;
    }
    __syncthreads();
    int i = blockIdx.x * 256 + tid;  // over NN*16 float4s
    if (i < NN * 16) {
        int row = i >> 4, f = (i & 15) * 4;
        f32x4 v = *(const f32x4*)(T + (size_t)row * 64 + f);
        s16x4 ub;
        #pragma unroll
        for (int j = 0; j < 4; j++) {
            float w = v[j] * sc[f + j] + sh[f + j];
            ub[j] = f2bs(w > 0.f ? w : 0.f);
        }
        *(s16x4*)((short*)Hb + (size_t)row * 64 + f) = ub;
    }
}

// ---- final MFMA GEMM: [h1(bf16) | relu(bn(T2))] (Nx128) @ Wtf -> fp32 out -----
__global__ void gemm_fin_k(const __hip_bfloat16* __restrict__ H1b,
                           const float* __restrict__ T2,
                           const float* __restrict__ stats,
                           const float* __restrict__ g, const float* __restrict__ be,
                           const short* __restrict__ Wtf,   // [n][k], k=128, bf16
                           const float* __restrict__ bias,
                           float* __restrict__ O) {
    __shared__ float sc[64], sh[64];
    int tid = threadIdx.x;
    if (tid < 64) {
        float mm = stats[tid] * (1.0f / NN);
        float var = stats[64 + tid] * (1.0f / NN) - mm * mm;
        if (var < 0.f) var = 0.f;
        float s = g[tid] * rsqrtf(var + BN_EPS);
        sc[tid] = s;
        sh[tid] = be[tid] - mm * s;
    }
    __syncthreads();
    int wv = tid >> 6, L = tid & 63;
    int m = L & 15, quad = L >> 4;
    int wrow = blockIdx.x * 64 + wv * 16;
    int arow = wrow + m;
    if (arow >= NN) arow = NN - 1;
    const short* Hp = (const short*)H1b;
    s16x8 a0 = *(const s16x8*)(Hp + (size_t)arow * 64 + quad * 8);
    s16x8 a1 = *(const s16x8*)(Hp + (size_t)arow * 64 + 32 + quad * 8);
    f32x4 t0 = *(const f32x4*)(T2 + (size_t)arow * 64 + quad * 8);
    f32x4 t1 = *(const f32x4*)(T2 + (size_t)arow * 64 + quad * 8 + 4);
    f32x4 t2 = *(const f32x4*)(T2 + (size_t)arow * 64 + 32 + quad * 8);
    f32x4 t3 = *(const f32x4*)(T2 + (size_t)arow * 64 + 32 + quad * 8 + 4);
    s16x8 a2, a3;
    #pragma unroll
    for (int j = 0; j < 4; j++) {
        int k0 = quad * 8 + j, k1 = quad * 8 + 4 + j;
        float u0 = t0[j] * sc[k0] + sh[k0]; a2[j]     = f2bs(u0 > 0.f ? u0 : 0.f);
        float u1 = t1[j] * sc[k1] + sh[k1]; a2[4 + j] = f2bs(u1 > 0.f ? u1 : 0.f);
        float u2 = t2[j] * sc[32 + k0] + sh[32 + k0]; a3[j]     = f2bs(u2 > 0.f ? u2 : 0.f);
        float u3 = t3[j] * sc[32 + k1] + sh[32 + k1]; a3[4 + j] = f2bs(u3 > 0.f ? u3 : 0.f);
    }
    f32x4 acc[4];
    #pragma unroll
    for (int nt = 0; nt < 4; nt++) {
        int n = nt * 16 + m;
        s16x8 b0 = *(const s16x8*)(Wtf + n * 128 + quad * 8);
        s16x8 b1 = *(const s16x8*)(Wtf + n * 128 + 32 + quad * 8);
        s16x8 b2 = *(const s16x8*)(Wtf + n * 128 + 64 + quad * 8);
        s16x8 b3 = *(const s16x8*)(Wtf + n * 128 + 96 + quad * 8);
        acc[nt] = (f32x4){0.f, 0.f, 0.f, 0.f};
        acc[nt] = __builtin_amdgcn_mfma_f32_16x16x32_bf16(a0, b0, acc[nt], 0, 0, 0);
        acc[nt] = __builtin_amdgcn_mfma_f32_16x16x32_bf16(a1, b1, acc[nt], 0, 0, 0);
        acc[nt] = __builtin_amdgcn_mfma_f32_16x16x32_bf16(a2, b2, acc[nt], 0, 0, 0);
        acc[nt] = __builtin_amdgcn_mfma_f32_16x16x32_bf16(a3, b3, acc[nt], 0, 0, 0);
    }
    #pragma unroll
    for (int nt = 0; nt < 4; nt++) {
        int col = nt * 16 + m;
        float bv = bias[col];
        #pragma unroll
        for (int r = 0; r < 4; r++) {
            int orow = wrow + quad * 4 + r;
            if (orow < NN) O[(size_t)orow * 64 + col] = acc[nt][r] + bv;
        }
    }
}

// ---------------- launch ----------------
extern "C" void kernel_launch(void* const* d_in, const int* in_sizes, int n_in,
                              void* d_out, int out_size, void* d_ws, size_t ws_size,
                              hipStream_t stream) {
    const float* x   = (const float*)d_in[0];
    const int*   ei  = (const int*)d_in[1];
    const float* w0a = (const float*)d_in[2];
    const float* b0a = (const float*)d_in[3];
    const float* g0a = (const float*)d_in[4];
    const float* be0a= (const float*)d_in[5];
    const float* w0b = (const float*)d_in[6];
    const float* b0b = (const float*)d_in[7];
    const float* g0b = (const float*)d_in[8];
    const float* be0b= (const float*)d_in[9];
    const float* w1a = (const float*)d_in[10];
    const float* b1a = (const float*)d_in[11];
    const float* g1a = (const float*)d_in[12];
    const float* be1a= (const float*)d_in[13];
    const float* w1b = (const float*)d_in[14];
    const float* b1b = (const float*)d_in[15];
    const float* g1b = (const float*)d_in[16];
    const float* be1b= (const float*)d_in[17];
    const float* lw  = (const float*)d_in[18];
    const float* lb  = (const float*)d_in[19];
    float* out = (float*)d_out;
    (void)in_sizes; (void)n_in; (void)out_size; (void)ws_size;

    char* wsb = (char*)d_ws;
    size_t o = 0;
    auto alloc = [&](size_t bytes) -> char* {
        char* p = wsb + o;
        o += (bytes + 255) & ~(size_t)255;
        return p;
    };
    int* part = (int*)alloc(NCH * 256 * 4);
    float* sums = (float*)alloc(512 * 4);
    int* bbase = (int*)alloc(257 * 4);
    int* bres = (int*)alloc(256 * 4);
    int* off = (int*)alloc((NN + 1) * 4);
    int* adj = (int*)alloc(NE * 4);
    int* ebuf = (int*)alloc(NE * 4);
    __hip_bfloat16* Xb  = (__hip_bfloat16*)alloc((size_t)NN * 64 * 2);
    __hip_bfloat16* HCb = (__hip_bfloat16*)alloc((size_t)NN * 64 * 2);
    float* T  = (float*)alloc((size_t)NN * 64 * 4);
    float* T2 = (float*)alloc((size_t)NN * 64 * 4);
    short* Wt0a = (short*)alloc(4096 * 2);
    short* Wt0b = (short*)alloc(4096 * 2);
    short* Wt1a = (short*)alloc(4096 * 2);
    short* Wt1b = (short*)alloc(4096 * 2);
    short* Wtf  = (short*)alloc(8192 * 2);

    const int* src = ei;
    const int* dst = ei + NE;

    prep_k<<<3326, 256, 0, stream>>>(dst, part, x, Xb, w0a, w0b, w1a, w1b, lw,
                                     Wt0a, Wt0b, Wt1a, Wt1b, Wtf);
    bscan_k<<<1, 256, 0, stream>>>(part, bbase, bres, off, sums);
    bscatter_k<<<NCH, 256, 0, stream>>>(src, dst, bres, ebuf);
    csr_k<<<NBK, 256, 0, stream>>>(bbase, ebuf, off, adj);

    const int mgrid = (NN + 63) / 64;          // 782
    const int agrid = (NN * 16 + 255) / 256;   // 3125

    // ---- layer 0 ----
    ggemm_k<<<mgrid, 256, 0, stream>>>(Xb, off, adj, Wt0a, b0a, T, sums + 0);
    gemm_bn_k<<<mgrid, 256, 0, stream>>>(T, sums + 0, g0a, be0a, Wt0b, b0b, T2, sums + 128);
    bn_k<<<agrid, 256, 0, stream>>>(T2, sums + 128, g0b, be0b, HCb);          // h1 bf16

    // ---- layer 1 ----
    ggemm_k<<<mgrid, 256, 0, stream>>>(HCb, off, adj, Wt1a, b1a, T, sums + 256);
    gemm_bn_k<<<mgrid, 256, 0, stream>>>(T, sums + 256, g1a, be1a, Wt1b, b1b, T2, sums + 384);

    // ---- JK cat + final linear (h2 BN fused; h1 read as bf16) ----
    gemm_fin_k<<<mgrid, 256, 0, stream>>>(HCb, T2, sums + 384, g1b, be1b, Wtf, lb, out);
}

// Round 14
// 318.558 us; speedup vs baseline: 3.0739x; 1.0107x over previous
//
#include <hip/hip_runtime.h>
#include <hip/hip_bf16.h>

#define NN 50000
#define NE 800000
#define BN_EPS 1e-5f
#define CHUNK 4096
#define NCH 196    // ceil(NE / CHUNK) = 196 (196*4096 = 802816)
#define NBK 196    // ceil(NN / 256) dst-buckets

typedef __attribute__((ext_vector_type(4))) float f32x4;
typedef __attribute__((ext_vector_type(8))) short s16x8;   // 8 bf16 = MFMA A/B frag
typedef __attribute__((ext_vector_type(4))) short s16x4;

__device__ __forceinline__ float bf2f(__hip_bfloat16 v) { return __bfloat162float(v); }
__device__ __forceinline__ float bs2f(short v) {
    unsigned u = ((unsigned)(unsigned short)v) << 16;
    return __builtin_bit_cast(float, u);
}
__device__ __forceinline__ short f2bs(float v) {
    __hip_bfloat16 b = __float2bfloat16(v);
    return __builtin_bit_cast(short, b);
}

// ---- prep: [0,196) bhist chunks -> part; [196,3321) cvt x->Xb; [3321,3326) W^T->bf16
__global__ void prep_k(const int* __restrict__ dst, int* __restrict__ part,
                       const float* __restrict__ x, __hip_bfloat16* __restrict__ Xb,
                       const float* __restrict__ w0a, const float* __restrict__ w0b,
                       const float* __restrict__ w1a, const float* __restrict__ w1b,
                       const float* __restrict__ lw,
                       short* __restrict__ Wt0a, short* __restrict__ Wt0b,
                       short* __restrict__ Wt1a, short* __restrict__ Wt1b,
                       short* __restrict__ Wtf) {
    int b = blockIdx.x, t = threadIdx.x;
    if (b < NCH) {
        __shared__ int c[256];
        c[t] = 0;
        __syncthreads();
        int base = b * CHUNK;
        int n = NE - base; if (n > CHUNK) n = CHUNK;
        for (int i = t; i < n; i += 256) atomicAdd(&c[dst[base + i] >> 8], 1);
        __syncthreads();
        part[b * 256 + t] = c[t];
    } else if (b < 196 + 3125) {
        int i = (b - 196) * 256 + t;  // over NN*16 = 800000 float4s
        if (i < NN * 16) {
            f32x4 v = *(const f32x4*)(x + (size_t)i * 4);
            s16x4 ov;
            #pragma unroll
            for (int j = 0; j < 4; j++) ov[j] = f2bs(v[j]);
            *(s16x4*)((short*)Xb + (size_t)i * 4) = ov;
        }
    } else {
        int wb = b - 3321;
        if (wb < 4) {
            const float* W = wb == 0 ? w0a : wb == 1 ? w0b : wb == 2 ? w1a : w1b;
            short* Wt = wb == 0 ? Wt0a : wb == 1 ? Wt0b : wb == 2 ? Wt1a : Wt1b;
            for (int e = t; e < 4096; e += 256) {
                int k = e >> 6, n = e & 63;
                Wt[n * 64 + k] = f2bs(W[e]);
            }
        } else {
            for (int e = t; e < 8192; e += 256) {
                int k = e >> 6, n = e & 63;
                Wtf[n * 128 + k] = f2bs(lw[e]);
            }
        }
    }
}

// ---- scan bucket totals (sum part over chunks) -> bbase/bres; zero sums -------
__global__ void bscan_k(const int* __restrict__ part, int* __restrict__ bbase,
                        int* __restrict__ bres, int* __restrict__ off,
                        float* __restrict__ sums) {
    __shared__ int s[256];
    int t = threadIdx.x;
    int v = 0;
    for (int c = 0; c < NCH; c++) v += part[c * 256 + t];
    s[t] = v;
    __syncthreads();
    for (int d = 1; d < 256; d <<= 1) {
        int u = (t >= d) ? s[t - d] : 0;
        __syncthreads();
        s[t] += u;
        __syncthreads();
    }
    int ex = s[t] - v;
    bbase[t] = ex;
    bres[t] = ex;
    if (t == 0) { bbase[256] = NE; off[NN] = NE; }
    sums[t] = 0.f; sums[256 + t] = 0.f;  // 512 floats total
}

// ---- bucket scatter: chunk -> bucket-ordered ebuf (coalesced writes) ----------
// packed int: src (16b) | dst&255 (8b) | bucket (8b)
__global__ void bscatter_k(const int* __restrict__ src, const int* __restrict__ dst,
                           int* __restrict__ bres, int* __restrict__ ebuf) {
    __shared__ int cnt[256], loff[256], lcur[256], gst[256], sc[256];
    __shared__ int packed[CHUNK];
    int t = threadIdx.x;
    cnt[t] = 0;
    __syncthreads();
    int base = blockIdx.x * CHUNK;
    int n = NE - base; if (n > CHUNK) n = CHUNK;
    for (int i = t; i < n; i += 256) atomicAdd(&cnt[dst[base + i] >> 8], 1);
    __syncthreads();
    sc[t] = cnt[t];
    __syncthreads();
    for (int d = 1; d < 256; d <<= 1) {
        int u = (t >= d) ? sc[t - d] : 0;
        __syncthreads();
        sc[t] += u;
        __syncthreads();
    }
    loff[t] = sc[t] - cnt[t];
    lcur[t] = loff[t];
    __syncthreads();
    for (int i = t; i < n; i += 256) {
        int d = dst[base + i];
        int b = d >> 8;
        int p = atomicAdd(&lcur[b], 1);
        packed[p] = src[base + i] | ((d & 255) << 16) | (b << 24);
    }
    __syncthreads();
    if (cnt[t]) gst[t] = atomicAdd(&bres[t], cnt[t]);
    __syncthreads();
    for (int i = t; i < n; i += 256) {
        int v = packed[i];
        int b = (v >> 24) & 255;
        ebuf[gst[b] + i - loff[b]] = v & 0xFFFFFF;
    }
}

// ---- per-bucket CSR: off[] + adj[] --------------------------------------------
__global__ void csr_k(const int* __restrict__ bbase, const int* __restrict__ ebuf,
                      int* __restrict__ off, int* __restrict__ adj) {
    __shared__ int cnt[256], loff[256], lcur[256], sc[256];
    int b = blockIdx.x, t = threadIdx.x;
    int s0 = bbase[b], s1 = bbase[b + 1];
    int n = s1 - s0;
    cnt[t] = 0;
    __syncthreads();
    for (int i = t; i < n; i += 256) atomicAdd(&cnt[(ebuf[s0 + i] >> 16) & 255], 1);
    __syncthreads();
    sc[t] = cnt[t];
    __syncthreads();
    for (int d = 1; d < 256; d <<= 1) {
        int u = (t >= d) ? sc[t - d] : 0;
        __syncthreads();
        sc[t] += u;
        __syncthreads();
    }
    loff[t] = sc[t] - cnt[t];
    lcur[t] = loff[t];
    int node = b * 256 + t;
    if (node < NN) off[node] = s0 + loff[t];
    __syncthreads();
    for (int i = t; i < n; i += 256) {
        int v = ebuf[s0 + i];
        int p = atomicAdd(&lcur[(v >> 16) & 255], 1);
        adj[s0 + p] = v & 0xFFFF;
    }
}

// ---- FUSED gather + MFMA GEMM + bias + BN stats -> T fp32 ---------------------
// wave = 16 nodes x 64 cols; lane L serves node m=(L&15), feature slices
// [quad*8,+8) and [32+quad*8,+8). Occupancy is grid-capped (~3 waves/SIMD), so
// VGPRs are free: 8-edge pipeline = 16 outstanding 16B loads per lane.
__global__ void ggemm_k(const __hip_bfloat16* __restrict__ X,
                        const int* __restrict__ off, const int* __restrict__ adj,
                        const short* __restrict__ Wt,    // 64x64 bf16, [n][k]
                        const float* __restrict__ bias,
                        float* __restrict__ T,
                        float* __restrict__ sums) {
    __shared__ float lsum[64], lssq[64];
    int t = threadIdx.x;
    if (t < 64) { lsum[t] = 0.f; lssq[t] = 0.f; }
    __syncthreads();
    int wv = t >> 6, L = t & 63;
    int m = L & 15, quad = L >> 4;
    int wrow = blockIdx.x * 64 + wv * 16;
    int node = wrow + m;
    if (node >= NN) node = NN - 1;  // dup row; stores/stats guarded below
    const short* Xp = (const short*)X;

    // self row slice
    const short* rp = Xp + (size_t)node * 64 + quad * 8;
    s16x8 sl = *(const s16x8*)rp;
    s16x8 shh = *(const s16x8*)(rp + 32);
    float aL[8], aH[8];
    #pragma unroll
    for (int j = 0; j < 8; j++) { aL[j] = bs2f(sl[j]); aH[j] = bs2f(shh[j]); }

    int s = off[node], e = off[node + 1];
    int p = s;
    // 8-edge pipeline: 16 independent 16B loads in flight per lane
    for (; p + 8 <= e; p += 8) {
        int jx[8];
        #pragma unroll
        for (int q = 0; q < 8; q++) jx[q] = adj[p + q];
        s16x8 v[8], w[8];
        #pragma unroll
        for (int q = 0; q < 8; q++) {
            const short* r = Xp + (size_t)jx[q] * 64 + quad * 8;
            v[q] = *(const s16x8*)r;
            w[q] = *(const s16x8*)(r + 32);
        }
        #pragma unroll
        for (int j = 0; j < 8; j++) {
            float sv = ((bs2f(v[0][j]) + bs2f(v[1][j])) + (bs2f(v[2][j]) + bs2f(v[3][j])))
                     + ((bs2f(v[4][j]) + bs2f(v[5][j])) + (bs2f(v[6][j]) + bs2f(v[7][j])));
            float sw = ((bs2f(w[0][j]) + bs2f(w[1][j])) + (bs2f(w[2][j]) + bs2f(w[3][j])))
                     + ((bs2f(w[4][j]) + bs2f(w[5][j])) + (bs2f(w[6][j]) + bs2f(w[7][j])));
            aL[j] += sv;
            aH[j] += sw;
        }
    }
    if (p + 4 <= e) {
        int j0 = adj[p], j1 = adj[p + 1], j2 = adj[p + 2], j3 = adj[p + 3];
        const short* r0 = Xp + (size_t)j0 * 64 + quad * 8;
        const short* r1 = Xp + (size_t)j1 * 64 + quad * 8;
        const short* r2 = Xp + (size_t)j2 * 64 + quad * 8;
        const short* r3 = Xp + (size_t)j3 * 64 + quad * 8;
        s16x8 v0 = *(const s16x8*)r0, w0 = *(const s16x8*)(r0 + 32);
        s16x8 v1 = *(const s16x8*)r1, w1 = *(const s16x8*)(r1 + 32);
        s16x8 v2 = *(const s16x8*)r2, w2 = *(const s16x8*)(r2 + 32);
        s16x8 v3 = *(const s16x8*)r3, w3 = *(const s16x8*)(r3 + 32);
        #pragma unroll
        for (int j = 0; j < 8; j++) {
            aL[j] += (bs2f(v0[j]) + bs2f(v1[j])) + (bs2f(v2[j]) + bs2f(v3[j]));
            aH[j] += (bs2f(w0[j]) + bs2f(w1[j])) + (bs2f(w2[j]) + bs2f(w3[j]));
        }
        p += 4;
    }
    for (; p < e; p++) {
        int j0 = adj[p];
        const short* r0 = Xp + (size_t)j0 * 64 + quad * 8;
        s16x8 v0 = *(const s16x8*)r0, w0 = *(const s16x8*)(r0 + 32);
        #pragma unroll
        for (int j = 0; j < 8; j++) { aL[j] += bs2f(v0[j]); aH[j] += bs2f(w0[j]); }
    }

    s16x8 a0, a1;
    #pragma unroll
    for (int j = 0; j < 8; j++) { a0[j] = f2bs(aL[j]); a1[j] = f2bs(aH[j]); }

    f32x4 acc[4];
    #pragma unroll
    for (int nt = 0; nt < 4; nt++) {
        int n = nt * 16 + m;
        s16x8 b0 = *(const s16x8*)(Wt + n * 64 + quad * 8);
        s16x8 b1 = *(const s16x8*)(Wt + n * 64 + 32 + quad * 8);
        acc[nt] = (f32x4){0.f, 0.f, 0.f, 0.f};
        acc[nt] = __builtin_amdgcn_mfma_f32_16x16x32_bf16(a0, b0, acc[nt], 0, 0, 0);
        acc[nt] = __builtin_amdgcn_mfma_f32_16x16x32_bf16(a1, b1, acc[nt], 0, 0, 0);
    }
    #pragma unroll
    for (int nt = 0; nt < 4; nt++) {
        int col = nt * 16 + m;
        float bv = bias[col];
        float ps = 0.f, pq = 0.f;
        #pragma unroll
        for (int r = 0; r < 4; r++) {
            int orow = wrow + quad * 4 + r;
            if (orow < NN) {
                float v = acc[nt][r] + bv;
                T[(size_t)orow * 64 + col] = v;
                ps += v;
                pq += v * v;
            }
        }
        atomicAdd(&lsum[col], ps);
        atomicAdd(&lssq[col], pq);
    }
    __syncthreads();
    if (t < 64) {
        atomicAdd(&sums[t], lsum[t]);
        atomicAdd(&sums[64 + t], lssq[t]);
    }
}

// ---- GEMM with A = relu(bn(T)) built on the fly -> Tout fp32 + stats ----------
__global__ void gemm_bn_k(const float* __restrict__ Tin,
                          const float* __restrict__ stats,
                          const float* __restrict__ g, const float* __restrict__ be,
                          const short* __restrict__ Wt,    // 64x64 bf16 [n][k]
                          const float* __restrict__ bias,
                          float* __restrict__ T,
                          float* __restrict__ sums) {
    __shared__ float sc[64], sh[64], lsum[64], lssq[64];
    int tid = threadIdx.x;
    if (tid < 64) {
        float mm = stats[tid] * (1.0f / NN);
        float var = stats[64 + tid] * (1.0f / NN) - mm * mm;
        if (var < 0.f) var = 0.f;
        float s = g[tid] * rsqrtf(var + BN_EPS);
        sc[tid] = s;
        sh[tid] = be[tid] - mm * s;
        lsum[tid] = 0.f; lssq[tid] = 0.f;
    }
    __syncthreads();
    int wv = tid >> 6, L = tid & 63;
    int m = L & 15, quad = L >> 4;
    int wrow = blockIdx.x * 64 + wv * 16;
    int arow = wrow + m;
    if (arow >= NN) arow = NN - 1;
    f32x4 t0 = *(const f32x4*)(Tin + (size_t)arow * 64 + quad * 8);
    f32x4 t1 = *(const f32x4*)(Tin + (size_t)arow * 64 + quad * 8 + 4);
    f32x4 t2 = *(const f32x4*)(Tin + (size_t)arow * 64 + 32 + quad * 8);
    f32x4 t3 = *(const f32x4*)(Tin + (size_t)arow * 64 + 32 + quad * 8 + 4);
    s16x8 a0, a1;
    #pragma unroll
    for (int j = 0; j < 4; j++) {
        int k0 = quad * 8 + j, k1 = quad * 8 + 4 + j;
        float u0 = t0[j] * sc[k0] + sh[k0]; a0[j]     = f2bs(u0 > 0.f ? u0 : 0.f);
        float u1 = t1[j] * sc[k1] + sh[k1]; a0[4 + j] = f2bs(u1 > 0.f ? u1 : 0.f);
        float u2 = t2[j] * sc[32 + k0] + sh[32 + k0]; a1[j]     = f2bs(u2 > 0.f ? u2 : 0.f);
        float u3 = t3[j] * sc[32 + k1] + sh[32 + k1]; a1[4 + j] = f2bs(u3 > 0.f ? u3 : 0.f);
    }
    f32x4 acc[4];
    #pragma unroll
    for (int nt = 0; nt < 4; nt++) {
        int n = nt * 16 + m;
        s16x8 b0 = *(const s16x8*)(Wt + n * 64 + quad * 8);
        s16x8 b1 = *(const s16x8*)(Wt + n * 64 + 32 + quad * 8);
        acc[nt] = (f32x4){0.f, 0.f, 0.f, 0.f};
        acc[nt] = __builtin_amdgcn_mfma_f32_16x16x32_bf16(a0, b0, acc[nt], 0, 0, 0);
        acc[nt] = __builtin_amdgcn_mfma_f32_16x16x32_bf16(a1, b1, acc[nt], 0, 0, 0);
    }
    #pragma unroll
    for (int nt = 0; nt < 4; nt++) {
        int col = nt * 16 + m;
        float bv = bias[col];
        float ps = 0.f, pq = 0.f;
        #pragma unroll
        for (int r = 0; r < 4; r++) {
            int orow = wrow + quad * 4 + r;
            if (orow < NN) {
                float v = acc[nt][r] + bv;
                T[(size_t)orow * 64 + col] = v;
                ps += v;
                pq += v * v;
            }
        }
        atomicAdd(&lsum[col], ps);
        atomicAdd(&lssq[col], pq);
    }
    __syncthreads();
    if (tid < 64) {
        atomicAdd(&sums[tid], lsum[tid]);
        atomicAdd(&sums[64 + tid], lssq[tid]);
    }
}

// ---- BN finalize + apply + ReLU: T2 fp32 -> HCb bf16 --------------------------
__global__ void bn_k(const float* __restrict__ T, const float* __restrict__ sums,
                     const float* __restrict__ g, const float* __restrict__ be,
                     __hip_bfloat16* __restrict__ Hb) {
    __shared__ float sc[64], sh[64];
    int tid = threadIdx.x;
    if (tid < 64) {
        float m = sums[tid] * (1.0f / NN);
        float var = sums[64 + tid] * (1.0f / NN) - m * m;
        if (var < 0.f) var = 0.f;
        float s = g[tid] * rsqrtf(var + BN_EPS);
        sc[tid] = s;
        sh[tid] = be[tid] - m * s;
    }
    __syncthreads();
    int i = blockIdx.x * 256 + tid;  // over NN*16 float4s
    if (i < NN * 16) {
        int row = i >> 4, f = (i & 15) * 4;
        f32x4 v = *(const f32x4*)(T + (size_t)row * 64 + f);
        s16x4 ub;
        #pragma unroll
        for (int j = 0; j < 4; j++) {
            float w = v[j] * sc[f + j] + sh[f + j];
            ub[j] = f2bs(w > 0.f ? w : 0.f);
        }
        *(s16x4*)((short*)Hb + (size_t)row * 64 + f) = ub;
    }
}

// ---- final MFMA GEMM: [h1(bf16) | relu(bn(T2))] (Nx128) @ Wtf -> fp32 out -----
__global__ void gemm_fin_k(const __hip_bfloat16* __restrict__ H1b,
                           const float* __restrict__ T2,
                           const float* __restrict__ stats,
                           const float* __restrict__ g, const float* __restrict__ be,
                           const short* __restrict__ Wtf,   // [n][k], k=128, bf16
                           const float* __restrict__ bias,
                           float* __restrict__ O) {
    __shared__ float sc[64], sh[64];
    int tid = threadIdx.x;
    if (tid < 64) {
        float mm = stats[tid] * (1.0f / NN);
        float var = stats[64 + tid] * (1.0f / NN) - mm * mm;
        if (var < 0.f) var = 0.f;
        float s = g[tid] * rsqrtf(var + BN_EPS);
        sc[tid] = s;
        sh[tid] = be[tid] - mm * s;
    }
    __syncthreads();
    int wv = tid >> 6, L = tid & 63;
    int m = L & 15, quad = L >> 4;
    int wrow = blockIdx.x * 64 + wv * 16;
    int arow = wrow + m;
    if (arow >= NN) arow = NN - 1;
    const short* Hp = (const short*)H1b;
    s16x8 a0 = *(const s16x8*)(Hp + (size_t)arow * 64 + quad * 8);
    s16x8 a1 = *(const s16x8*)(Hp + (size_t)arow * 64 + 32 + quad * 8);
    f32x4 t0 = *(const f32x4*)(T2 + (size_t)arow * 64 + quad * 8);
    f32x4 t1 = *(const f32x4*)(T2 + (size_t)arow * 64 + quad * 8 + 4);
    f32x4 t2 = *(const f32x4*)(T2 + (size_t)arow * 64 + 32 + quad * 8);
    f32x4 t3 = *(const f32x4*)(T2 + (size_t)arow * 64 + 32 + quad * 8 + 4);
    s16x8 a2, a3;
    #pragma unroll
    for (int j = 0; j < 4; j++) {
        int k0 = quad * 8 + j, k1 = quad * 8 + 4 + j;
        float u0 = t0[j] * sc[k0] + sh[k0]; a2[j]     = f2bs(u0 > 0.f ? u0 : 0.f);
        float u1 = t1[j] * sc[k1] + sh[k1]; a2[4 + j] = f2bs(u1 > 0.f ? u1 : 0.f);
        float u2 = t2[j] * sc[32 + k0] + sh[32 + k0]; a3[j]     = f2bs(u2 > 0.f ? u2 : 0.f);
        float u3 = t3[j] * sc[32 + k1] + sh[32 + k1]; a3[4 + j] = f2bs(u3 > 0.f ? u3 : 0.f);
    }
    f32x4 acc[4];
    #pragma unroll
    for (int nt = 0; nt < 4; nt++) {
        int n = nt * 16 + m;
        s16x8 b0 = *(const s16x8*)(Wtf + n * 128 + quad * 8);
        s16x8 b1 = *(const s16x8*)(Wtf + n * 128 + 32 + quad * 8);
        s16x8 b2 = *(const s16x8*)(Wtf + n * 128 + 64 + quad * 8);
        s16x8 b3 = *(const s16x8*)(Wtf + n * 128 + 96 + quad * 8);
        acc[nt] = (f32x4){0.f, 0.f, 0.f, 0.f};
        acc[nt] = __builtin_amdgcn_mfma_f32_16x16x32_bf16(a0, b0, acc[nt], 0, 0, 0);
        acc[nt] = __builtin_amdgcn_mfma_f32_16x16x32_bf16(a1, b1, acc[nt], 0, 0, 0);
        acc[nt] = __builtin_amdgcn_mfma_f32_16x16x32_bf16(a2, b2, acc[nt], 0, 0, 0);
        acc[nt] = __builtin_amdgcn_mfma_f32_16x16x32_bf16(a3, b3, acc[nt], 0, 0, 0);
    }
    #pragma unroll
    for (int nt = 0; nt < 4; nt++) {
        int col = nt * 16 + m;
        float bv = bias[col];
        #pragma unroll
        for (int r = 0; r < 4; r++) {
            int orow = wrow + quad * 4 + r;
            if (orow < NN) O[(size_t)orow * 64 + col] = acc[nt][r] + bv;
        }
    }
}

// ---------------- launch ----------------
extern "C" void kernel_launch(void* const* d_in, const int* in_sizes, int n_in,
                              void* d_out, int out_size, void* d_ws, size_t ws_size,
                              hipStream_t stream) {
    const float* x   = (const float*)d_in[0];
    const int*   ei  = (const int*)d_in[1];
    const float* w0a = (const float*)d_in[2];
    const float* b0a = (const float*)d_in[3];
    const float* g0a = (const float*)d_in[4];
    const float* be0a= (const float*)d_in[5];
    const float* w0b = (const float*)d_in[6];
    const float* b0b = (const float*)d_in[7];
    const float* g0b = (const float*)d_in[8];
    const float* be0b= (const float*)d_in[9];
    const float* w1a = (const float*)d_in[10];
    const float* b1a = (const float*)d_in[11];
    const float* g1a = (const float*)d_in[12];
    const float* be1a= (const float*)d_in[13];
    const float* w1b = (const float*)d_in[14];
    const float* b1b = (const float*)d_in[15];
    const float* g1b = (const float*)d_in[16];
    const float* be1b= (const float*)d_in[17];
    const float* lw  = (const float*)d_in[18];
    const float* lb  = (const float*)d_in[19];
    float* out = (float*)d_out;
    (void)in_sizes; (void)n_in; (void)out_size; (void)ws_size;

    char* wsb = (char*)d_ws;
    size_t o = 0;
    auto alloc = [&](size_t bytes) -> char* {
        char* p = wsb + o;
        o += (bytes + 255) & ~(size_t)255;
        return p;
    };
    int* part = (int*)alloc(NCH * 256 * 4);
    float* sums = (float*)alloc(512 * 4);
    int* bbase = (int*)alloc(257 * 4);
    int* bres = (int*)alloc(256 * 4);
    int* off = (int*)alloc((NN + 1) * 4);
    int* adj = (int*)alloc(NE * 4);
    int* ebuf = (int*)alloc(NE * 4);
    __hip_bfloat16* Xb  = (__hip_bfloat16*)alloc((size_t)NN * 64 * 2);
    __hip_bfloat16* HCb = (__hip_bfloat16*)alloc((size_t)NN * 64 * 2);
    float* T  = (float*)alloc((size_t)NN * 64 * 4);
    float* T2 = (float*)alloc((size_t)NN * 64 * 4);
    short* Wt0a = (short*)alloc(4096 * 2);
    short* Wt0b = (short*)alloc(4096 * 2);
    short* Wt1a = (short*)alloc(4096 * 2);
    short* Wt1b = (short*)alloc(4096 * 2);
    short* Wtf  = (short*)alloc(8192 * 2);

    const int* src = ei;
    const int* dst = ei + NE;

    prep_k<<<3326, 256, 0, stream>>>(dst, part, x, Xb, w0a, w0b, w1a, w1b, lw,
                                     Wt0a, Wt0b, Wt1a, Wt1b, Wtf);
    bscan_k<<<1, 256, 0, stream>>>(part, bbase, bres, off, sums);
    bscatter_k<<<NCH, 256, 0, stream>>>(src, dst, bres, ebuf);
    csr_k<<<NBK, 256, 0, stream>>>(bbase, ebuf, off, adj);

    const int mgrid = (NN + 63) / 64;          // 782
    const int agrid = (NN * 16 + 255) / 256;   // 3125

    // ---- layer 0 ----
    ggemm_k<<<mgrid, 256, 0, stream>>>(Xb, off, adj, Wt0a, b0a, T, sums + 0);
    gemm_bn_k<<<mgrid, 256, 0, stream>>>(T, sums + 0, g0a, be0a, Wt0b, b0b, T2, sums + 128);
    bn_k<<<agrid, 256, 0, stream>>>(T2, sums + 128, g0b, be0b, HCb);          // h1 bf16

    // ---- layer 1 ----
    ggemm_k<<<mgrid, 256, 0, stream>>>(HCb, off, adj, Wt1a, b1a, T, sums + 256);
    gemm_bn_k<<<mgrid, 256, 0, stream>>>(T, sums + 256, g1a, be1a, Wt1b, b1b, T2, sums + 384);

    // ---- JK cat + final linear (h2 BN fused; h1 read as bf16) ----
    gemm_fin_k<<<mgrid, 256, 0, stream>>>(HCb, T2, sums + 384, g1b, be1b, Wtf, lb, out);
}